// Round 1
// baseline (556.108 us; speedup 1.0000x reference)
//
#include <hip/hip_runtime.h>
#include <cstdint>
#include <cstddef>

typedef unsigned short u16;
typedef unsigned int   u32;
typedef long long      i64;

#define N_NODES 50000
#define N_EDGES 1600000
#define DIM     128
#define NHEADS  4
#define NEG_SLOPE 0.2f

__device__ __forceinline__ float b2f(u16 u) {
    union { u32 u; float f; } v; v.u = ((u32)u) << 16; return v.f;
}
__device__ __forceinline__ float bflo(u32 w) {
    union { u32 u; float f; } v; v.u = w << 16; return v.f;
}
__device__ __forceinline__ float bfhi(u32 w) {
    union { u32 u; float f; } v; v.u = w & 0xffff0000u; return v.f;
}
__device__ __forceinline__ u16 f2b(float f) {
    union { float f; u32 u; } v; v.f = f;
    u32 u = v.u;
    u32 r = (u + 0x7fffu + ((u >> 16) & 1u)) >> 16;
    return (u16)r;
}
__device__ __forceinline__ float leaky(float v) {
    return v >= 0.f ? v : NEG_SLOPE * v;
}
// f=1: fp32 storage; f=0: packed bf16
__device__ __forceinline__ float fload(const void* p, int f, int idx) {
    return f ? ((const float*)p)[idx] : b2f(((const u16*)p)[idx]);
}
// edge_index stored (2, E) row-major: elem[e]=row_e, elem[E+e]=col_e
__device__ __forceinline__ int eload(const void* ei, int f64, int idx) {
    return f64 ? (int)((const i64*)ei)[idx] : ((const int*)ei)[idx];
}

// ---------------------------------------------------------------------------
// K0: storage detection. flags: [0]=x [1]=Wq [2]=Wk [3]=Wl [4]=bl [5]=ei-int64
// (validated r9/r10)
// ---------------------------------------------------------------------------
__device__ __forceinline__ int fp32_vote(const u32* p, int K, int lane) {
    int bad = 0;
    for (int i = lane; i < K; i += 64) {
        const u32 w = p[i];
        const u16 lo = (u16)(w & 0xffff);
        const float v = b2f(lo);
        if (lo == 0 || !(fabsf(v) < 1e4f)) ++bad;
    }
    #pragma unroll
    for (int off = 32; off > 0; off >>= 1) bad += __shfl_down(bad, off);
    return bad;
}

__global__ __launch_bounds__(64) void detect_all_kernel(
    const u32* __restrict__ x,  const u32* __restrict__ wq,
    const u32* __restrict__ wk, const u32* __restrict__ wl,
    const u32* __restrict__ bl, const u32* __restrict__ ei,
    int* __restrict__ flags)
{
    const int lane = threadIdx.x;
    int b;
    b = fp32_vote(x,  256, lane); if (lane == 0) flags[0] = (b > 64);
    b = fp32_vote(wq, 128, lane); if (lane == 0) flags[1] = (b > 32);
    b = fp32_vote(wk, 128, lane); if (lane == 0) flags[2] = (b > 32);
    b = fp32_vote(wl, 256, lane); if (lane == 0) flags[3] = (b > 64);
    b = fp32_vote(bl,  64, lane); if (lane == 0) flags[4] = (b > 16);
    int z = 0;
    for (int i = lane; i < 256; i += 64)
        if (ei[2 * i + 1] == 0) ++z;
    #pragma unroll
    for (int off = 32; off > 0; off >>= 1) z += __shfl_down(z, off);
    if (lane == 0) flags[5] = (z > 128);
}

// ---------------------------------------------------------------------------
#define W_TOTAL (512 + 512 + 16384 + 128)
__global__ __launch_bounds__(256) void canon_w_kernel(
    const void* __restrict__ Wq, const void* __restrict__ Wk,
    const void* __restrict__ Wl, const void* __restrict__ bl,
    const int* __restrict__ flags, float* __restrict__ wf)
{
    const int i = blockIdx.x * 256 + threadIdx.x;
    if (i >= W_TOTAL) return;
    const void* src; int j, f;
    if (i < 512)         { src = Wq; j = i;         f = flags[1]; }
    else if (i < 1024)   { src = Wk; j = i - 512;   f = flags[2]; }
    else if (i < 17408)  { src = Wl; j = i - 1024;  f = flags[3]; }
    else                 { src = bl; j = i - 17408; f = flags[4]; }
    wf[i] = fload(src, f, j);
}

// ---------------------------------------------------------------------------
// K1 v2: h_proj (bf16 storage) = x @ Wl^T + bl
// ---------------------------------------------------------------------------
#define PB_NODES 32
__global__ __launch_bounds__(512) void proj_kernel(
    const void* __restrict__ x, const int* __restrict__ flags,
    const float* __restrict__ wf, u16* __restrict__ h_projb)
{
    __shared__ u32  sWT32[64 * DIM];     // 32 KB
    __shared__ float sx[4][DIM];         // 2 KB
    const int t = threadIdx.x;
    const int o = t & 127;               // output dim
    const int g = t >> 7;                // node group 0..3
    const int fx = flags[0];
    const float* Wl = wf + 1024;
    const float* bl = wf + 17408;

    for (int i = t; i < 64 * DIM; i += 512) {
        const int k2 = i >> 7;
        const int oo = i & 127;
        const float w0 = Wl[oo * DIM + 2 * k2];
        const float w1 = Wl[oo * DIM + 2 * k2 + 1];
        sWT32[i] = (u32)f2b(w0) | ((u32)f2b(w1) << 16);
    }
    const float blv = bl[o];

    for (int rep = 0; rep < 8; ++rep) {
        const int n = blockIdx.x * PB_NODES + rep * 4 + g;
        __syncthreads();
        if (n < N_NODES) sx[g][o] = fload(x, fx, n * DIM + o);
        __syncthreads();
        if (n >= N_NODES) continue;
        float acc0 = blv, acc1 = 0.f;
        #pragma unroll 8
        for (int k2 = 0; k2 < 64; ++k2) {
            const u32 w = sWT32[k2 * DIM + o];
            acc0 = fmaf(sx[g][2 * k2],     b2f((u16)(w & 0xffff)), acc0);
            acc1 = fmaf(sx[g][2 * k2 + 1], b2f((u16)(w >> 16)),    acc1);
        }
        h_projb[n * DIM + o] = f2b(acc0 + acc1);
    }
}

// ---------------------------------------------------------------------------
// K2: h_q = x@Wq^T, k_act = leaky(x@Wk^T)   (validated r9/r10)
// ---------------------------------------------------------------------------
__global__ __launch_bounds__(256) void qk_kernel(
    const void* __restrict__ x, const int* __restrict__ flags,
    const float* __restrict__ wf,
    float* __restrict__ h_q, float* __restrict__ k_act)
{
    const int wave = threadIdx.x >> 6, lane = threadIdx.x & 63;
    const int n = blockIdx.x * 4 + wave;
    if (n >= N_NODES) return;
    const int fx = flags[0];
    const float x0 = fload(x, fx, n * DIM + 2 * lane);
    const float x1 = fload(x, fx, n * DIM + 2 * lane + 1);
    #pragma unroll
    for (int h = 0; h < NHEADS; ++h) {
        const float qx = wf[h * DIM + 2 * lane];
        const float qy = wf[h * DIM + 2 * lane + 1];
        const float kx = wf[512 + h * DIM + 2 * lane];
        const float ky = wf[512 + h * DIM + 2 * lane + 1];
        float pq = x0 * qx + x1 * qy;
        float pk = x0 * kx + x1 * ky;
        #pragma unroll
        for (int off = 32; off > 0; off >>= 1) {
            pq += __shfl_down(pq, off);
            pk += __shfl_down(pk, off);
        }
        if (lane == 0) {
            h_q[n * NHEADS + h]   = pq;
            k_act[n * NHEADS + h] = leaky(pk);
        }
    }
}

// ---------------------------------------------------------------------------
// K3: in-degree histogram
// ---------------------------------------------------------------------------
__global__ __launch_bounds__(256) void hist_kernel(
    const void* __restrict__ ei, const int* __restrict__ flags,
    int* __restrict__ deg)
{
    const int e = blockIdx.x * 256 + threadIdx.x;
    if (e < N_EDGES) atomicAdd(&deg[eload(ei, flags[5], e)], 1);
}

// ---------------------------------------------------------------------------
// K4: exclusive scan of deg -> offsets
// ---------------------------------------------------------------------------
__global__ __launch_bounds__(1024) void scan_kernel(
    const int* __restrict__ deg, int* __restrict__ offsets)
{
    __shared__ int part[1024];
    const int t = threadIdx.x;
    const int CH = (N_NODES + 1023) / 1024;   // 49
    const int base = t * CH;
    int s = 0;
    for (int i = 0; i < CH; ++i) {
        const int idx = base + i;
        if (idx < N_NODES) s += deg[idx];
    }
    part[t] = s;
    __syncthreads();
    for (int off = 1; off < 1024; off <<= 1) {
        const int v = (t >= off) ? part[t - off] : 0;
        __syncthreads();
        part[t] += v;
        __syncthreads();
    }
    int run = part[t] - s;
    for (int i = 0; i < CH; ++i) {
        const int idx = base + i;
        if (idx < N_NODES) { offsets[idx] = run; run += deg[idx]; }
    }
    if (t == 1023) offsets[N_NODES] = part[1023];
}

// ---------------------------------------------------------------------------
// K5: scatter edges into CSR slots
// ---------------------------------------------------------------------------
__global__ __launch_bounds__(256) void csr_kernel(
    const void* __restrict__ ei, const int* __restrict__ flags,
    const int* __restrict__ offsets, int* __restrict__ cursor,
    int* __restrict__ csr_col)
{
    const int e = blockIdx.x * 256 + threadIdx.x;
    if (e >= N_EDGES) return;
    const int fe = flags[5];
    const int r = eload(ei, fe, e);
    const int c = eload(ei, fe, N_EDGES + e);
    const int p = atomicAdd(&cursor[r], 1);
    csr_col[offsets[r] + p] = c;
}

// ---------------------------------------------------------------------------
// K6: q_agg[n] = sum over incoming edges of h_q[col]  (wave per node)
// ---------------------------------------------------------------------------
__global__ __launch_bounds__(256) void qagg_kernel(
    const int* __restrict__ offsets, const int* __restrict__ csr_col,
    const float* __restrict__ h_q, float* __restrict__ q_agg)
{
    const int wave = threadIdx.x >> 6, lane = threadIdx.x & 63;
    const int n = blockIdx.x * 4 + wave;
    if (n >= N_NODES) return;
    const int s0 = offsets[n], s1 = offsets[n + 1];
    float a0 = 0.f, a1 = 0.f, a2 = 0.f, a3 = 0.f;
    for (int s = s0 + lane; s < s1; s += 64) {
        const int c = csr_col[s];
        const float4 q = ((const float4*)h_q)[c];
        a0 += q.x; a1 += q.y; a2 += q.z; a3 += q.w;
    }
    #pragma unroll
    for (int off = 32; off > 0; off >>= 1) {
        a0 += __shfl_down(a0, off); a1 += __shfl_down(a1, off);
        a2 += __shfl_down(a2, off); a3 += __shfl_down(a3, off);
    }
    if (lane == 0) ((float4*)q_agg)[n] = make_float4(a0, a1, a2, a3);
}

// ---------------------------------------------------------------------------
// K7 v3: fused online softmax + weighted aggregation -> out fp32
//   - pass A caches scores + col for the first two 64-edge strides in regs
//     (covers degree <= 128; Poisson(32) degrees -> effectively all nodes;
//     generic recompute fallback retained for larger degrees)
//   - pass B processes TWO edges per step: lanes 0-31 take edge j, lanes
//     32-63 take edge j+1; per-lane load widens to dwordx2 (4 bf16 dims).
//     Halves VMEM ops and bpermutes per edge vs v2.
//   - cross-half __shfl_down(...,32) reduction, 32-lane float4 store.
// ---------------------------------------------------------------------------
__global__ __launch_bounds__(256) void attn_kernel(
    const int* __restrict__ offsets, const int* __restrict__ csr_col,
    const float* __restrict__ k_act, const float* __restrict__ q_agg,
    const u16* __restrict__ h_projb, float* __restrict__ out)
{
    const int wave = threadIdx.x >> 6, lane = threadIdx.x & 63;
    const int n = blockIdx.x * 4 + wave;
    if (n >= N_NODES) return;
    const int s0 = offsets[n], s1 = offsets[n + 1];
    const float4 k4 = ((const float4*)k_act)[n];

    // ---- pass A: online softmax (m, t) per head; cache strides 0 and 1 ----
    float m0 = -1e30f, m1 = -1e30f, m2 = -1e30f, m3 = -1e30f;
    float t0 = 0.f, t1 = 0.f, t2 = 0.f, t3 = 0.f;

    int cA = 0;
    float sA0 = -1e30f, sA1 = -1e30f, sA2 = -1e30f, sA3 = -1e30f;
    {
        const int s = s0 + lane;
        if (s < s1) {
            cA = csr_col[s];
            const float4 q = ((const float4*)q_agg)[cA];
            sA0 = k4.x * q.x; sA1 = k4.y * q.y;
            sA2 = k4.z * q.z; sA3 = k4.w * q.w;
            m0 = sA0; t0 = 1.f;  m1 = sA1; t1 = 1.f;   // first update exact
            m2 = sA2; t2 = 1.f;  m3 = sA3; t3 = 1.f;
        }
    }
    int cB = 0;
    float sB0 = -1e30f, sB1 = -1e30f, sB2 = -1e30f, sB3 = -1e30f;
    if (s1 - s0 > 64) {
        const int s = s0 + 64 + lane;
        if (s < s1) {
            cB = csr_col[s];
            const float4 q = ((const float4*)q_agg)[cB];
            sB0 = k4.x * q.x; sB1 = k4.y * q.y;
            sB2 = k4.z * q.z; sB3 = k4.w * q.w;
            float nm;
            nm = fmaxf(m0, sB0); t0 = t0 * __expf(m0 - nm) + __expf(sB0 - nm); m0 = nm;
            nm = fmaxf(m1, sB1); t1 = t1 * __expf(m1 - nm) + __expf(sB1 - nm); m1 = nm;
            nm = fmaxf(m2, sB2); t2 = t2 * __expf(m2 - nm) + __expf(sB2 - nm); m2 = nm;
            nm = fmaxf(m3, sB3); t3 = t3 * __expf(m3 - nm) + __expf(sB3 - nm); m3 = nm;
        }
    }
    // generic tail for degree > 128 (rare; pass B recomputes these)
    for (int s = s0 + 128 + lane; s < s1; s += 64) {
        const int c = csr_col[s];
        const float4 q = ((const float4*)q_agg)[c];
        float sc, nm;
        sc = k4.x * q.x; nm = fmaxf(m0, sc); t0 = t0 * __expf(m0 - nm) + __expf(sc - nm); m0 = nm;
        sc = k4.y * q.y; nm = fmaxf(m1, sc); t1 = t1 * __expf(m1 - nm) + __expf(sc - nm); m1 = nm;
        sc = k4.z * q.z; nm = fmaxf(m2, sc); t2 = t2 * __expf(m2 - nm) + __expf(sc - nm); m2 = nm;
        sc = k4.w * q.w; nm = fmaxf(m3, sc); t3 = t3 * __expf(m3 - nm) + __expf(sc - nm); m3 = nm;
    }
    #pragma unroll
    for (int off = 32; off > 0; off >>= 1) {
        float om, ot, nm;
        om = __shfl_xor(m0, off); ot = __shfl_xor(t0, off);
        nm = fmaxf(m0, om); t0 = t0 * __expf(m0 - nm) + ot * __expf(om - nm); m0 = nm;
        om = __shfl_xor(m1, off); ot = __shfl_xor(t1, off);
        nm = fmaxf(m1, om); t1 = t1 * __expf(m1 - nm) + ot * __expf(om - nm); m1 = nm;
        om = __shfl_xor(m2, off); ot = __shfl_xor(t2, off);
        nm = fmaxf(m2, om); t2 = t2 * __expf(m2 - nm) + ot * __expf(om - nm); m2 = nm;
        om = __shfl_xor(m3, off); ot = __shfl_xor(t3, off);
        nm = fmaxf(m3, om); t3 = t3 * __expf(m3 - nm) + ot * __expf(om - nm); m3 = nm;
    }
    const float r0 = 0.25f / (t0 + 1e-8f), r1 = 0.25f / (t1 + 1e-8f);
    const float r2 = 0.25f / (t2 + 1e-8f), r3 = 0.25f / (t3 + 1e-8f);

    // ---- pass B: dual-edge broadcast accumulate ----
    const int sub = lane & 31;          // dim group: dims 4*sub .. 4*sub+3
    const int eh  = lane >> 5;          // which edge of the pair this half takes
    float acc0 = 0.f, acc1 = 0.f, acc2 = 0.f, acc3 = 0.f;
    const uint2* hp2 = (const uint2*)h_projb;   // row stride = 32 uint2 (256 B)

    for (int base = s0; base < s1; base += 64) {
        int   c_s;
        float a_s;
        if (base == s0) {               // cached stride 0 (invalid lanes: exp->0)
            c_s = cA;
            a_s = __expf(sA0 - m0) * r0 + __expf(sA1 - m1) * r1
                + __expf(sA2 - m2) * r2 + __expf(sA3 - m3) * r3;
        } else if (base == s0 + 64) {   // cached stride 1
            c_s = cB;
            a_s = __expf(sB0 - m0) * r0 + __expf(sB1 - m1) * r1
                + __expf(sB2 - m2) * r2 + __expf(sB3 - m3) * r3;
        } else {                        // generic recompute (degree > 128)
            const int s = base + lane;
            c_s = 0; a_s = 0.f;
            if (s < s1) {
                c_s = csr_col[s];
                const float4 q = ((const float4*)q_agg)[c_s];
                a_s = __expf(k4.x * q.x - m0) * r0 + __expf(k4.y * q.y - m1) * r1
                    + __expf(k4.z * q.z - m2) * r2 + __expf(k4.w * q.w - m3) * r3;
            }
        }
        const int cnt = min(64, s1 - base);
        #pragma unroll 4
        for (int j = 0; j < cnt; j += 2) {
            // lanes 0-31 take edge j, lanes 32-63 take edge j+1; a==0 pads
            const int   c = __shfl(c_s, j + eh);
            const float a = __shfl(a_s, j + eh);
            const uint2 w = hp2[(size_t)c * 32 + sub];
            acc0 = fmaf(a, bflo(w.x), acc0);
            acc1 = fmaf(a, bfhi(w.x), acc1);
            acc2 = fmaf(a, bflo(w.y), acc2);
            acc3 = fmaf(a, bfhi(w.y), acc3);
        }
    }
    // combine the two halves, then 32-lane float4 store
    acc0 += __shfl_down(acc0, 32);
    acc1 += __shfl_down(acc1, 32);
    acc2 += __shfl_down(acc2, 32);
    acc3 += __shfl_down(acc3, 32);
    if (eh == 0)
        ((float4*)out)[(size_t)n * 32 + sub] =
            make_float4(leaky(acc0), leaky(acc1), leaky(acc2), leaky(acc3));
}

// ---------------------------------------------------------------------------
extern "C" void kernel_launch(void* const* d_in, const int* in_sizes, int n_in,
                              void* d_out, int out_size, void* d_ws, size_t ws_size,
                              hipStream_t stream)
{
    const void* x  = d_in[0];
    const void* ei = d_in[1];
    const void* Wq = d_in[2];
    const void* Wk = d_in[3];
    const void* Wl = d_in[4];
    const void* bl = d_in[5];
    float* out = (float*)d_out;   // reference output dtype = float32

    char* ws = (char*)d_ws;
    size_t off = 0;
    auto alloc = [&](size_t bytes) -> size_t {
        off = (off + 255) & ~(size_t)255;
        size_t o = off; off += bytes; return o;
    };
    const size_t o_flag  = alloc(256);
    const size_t o_wf    = alloc((size_t)W_TOTAL * sizeof(float));
    const size_t o_hq    = alloc((size_t)N_NODES * NHEADS * sizeof(float));
    const size_t o_kact  = alloc((size_t)N_NODES * NHEADS * sizeof(float));
    const size_t o_qagg  = alloc((size_t)N_NODES * NHEADS * sizeof(float));
    const size_t o_hproj = alloc((size_t)N_NODES * DIM * sizeof(u16));
    const size_t o_deg   = alloc((size_t)N_NODES * sizeof(int));   // zeroed
    const size_t o_cur   = alloc((size_t)N_NODES * sizeof(int));   // zeroed
    const size_t o_offs  = alloc((size_t)(N_NODES + 1) * sizeof(int));
    const size_t o_csr   = alloc((size_t)N_EDGES * sizeof(int));
    (void)ws_size;   // ~22 MB, ws_size proven >= 45.9 MB in r7

    int*   flags   = (int*)(ws + o_flag);
    float* wf      = (float*)(ws + o_wf);
    float* h_q     = (float*)(ws + o_hq);
    float* k_act   = (float*)(ws + o_kact);
    float* q_agg   = (float*)(ws + o_qagg);
    u16*   h_projb = (u16*)(ws + o_hproj);
    int*   deg     = (int*)(ws + o_deg);
    int*   cursor  = (int*)(ws + o_cur);
    int*   offsets = (int*)(ws + o_offs);
    int*   csr_col = (int*)(ws + o_csr);

    hipMemsetAsync(ws + o_deg, 0, o_offs - o_deg, stream);   // deg + cursor

    const int EB = (N_EDGES + 255) / 256;
    detect_all_kernel<<<1, 64, 0, stream>>>(
        (const u32*)x, (const u32*)Wq, (const u32*)Wk, (const u32*)Wl,
        (const u32*)bl, (const u32*)ei, flags);
    canon_w_kernel<<<(W_TOTAL + 255) / 256, 256, 0, stream>>>(Wq, Wk, Wl, bl, flags, wf);
    proj_kernel<<<(N_NODES + PB_NODES - 1) / PB_NODES, 512, 0, stream>>>(
        x, flags, wf, h_projb);
    qk_kernel<<<N_NODES / 4, 256, 0, stream>>>(x, flags, wf, h_q, k_act);
    hist_kernel<<<EB, 256, 0, stream>>>(ei, flags, deg);
    scan_kernel<<<1, 1024, 0, stream>>>(deg, offsets);
    csr_kernel<<<EB, 256, 0, stream>>>(ei, flags, offsets, cursor, csr_col);
    qagg_kernel<<<N_NODES / 4, 256, 0, stream>>>(offsets, csr_col, h_q, q_agg);
    attn_kernel<<<N_NODES / 4, 256, 0, stream>>>(offsets, csr_col, k_act, q_agg,
                                                 h_projb, out);
}

// Round 2
// 406.606 us; speedup vs baseline: 1.3677x; 1.3677x over previous
//
#include <hip/hip_runtime.h>
#include <cstdint>
#include <cstddef>

typedef unsigned short u16;
typedef unsigned int   u32;
typedef long long      i64;

#define N_NODES 50000
#define N_EDGES 1600000
#define DIM     128
#define NHEADS  4
#define NEG_SLOPE 0.2f
#define CAP     96          // fixed per-node CSR capacity (Poisson(32): P(deg>=96)~e^-41)

__device__ __forceinline__ float b2f(u16 u) {
    union { u32 u; float f; } v; v.u = ((u32)u) << 16; return v.f;
}
__device__ __forceinline__ float bflo(u32 w) {
    union { u32 u; float f; } v; v.u = w << 16; return v.f;
}
__device__ __forceinline__ float bfhi(u32 w) {
    union { u32 u; float f; } v; v.u = w & 0xffff0000u; return v.f;
}
__device__ __forceinline__ u16 f2b(float f) {
    union { float f; u32 u; } v; v.f = f;
    u32 u = v.u;
    u32 r = (u + 0x7fffu + ((u >> 16) & 1u)) >> 16;
    return (u16)r;
}
__device__ __forceinline__ float leaky(float v) {
    return v >= 0.f ? v : NEG_SLOPE * v;
}
// f=1: fp32 storage; f=0: packed bf16
__device__ __forceinline__ float fload(const void* p, int f, int idx) {
    return f ? ((const float*)p)[idx] : b2f(((const u16*)p)[idx]);
}
// edge_index stored (2, E) row-major: elem[e]=row_e, elem[E+e]=col_e
__device__ __forceinline__ int eload(const void* ei, int f64, int idx) {
    return f64 ? (int)((const i64*)ei)[idx] : ((const int*)ei)[idx];
}

// ---------------------------------------------------------------------------
// K0: storage detection. flags: [0]=x [1]=Wq [2]=Wk [3]=Wl [4]=bl [5]=ei-int64
// (validated r9/r10)
// ---------------------------------------------------------------------------
__device__ __forceinline__ int fp32_vote(const u32* p, int K, int lane) {
    int bad = 0;
    for (int i = lane; i < K; i += 64) {
        const u32 w = p[i];
        const u16 lo = (u16)(w & 0xffff);
        const float v = b2f(lo);
        if (lo == 0 || !(fabsf(v) < 1e4f)) ++bad;
    }
    #pragma unroll
    for (int off = 32; off > 0; off >>= 1) bad += __shfl_down(bad, off);
    return bad;
}

__global__ __launch_bounds__(64) void detect_all_kernel(
    const u32* __restrict__ x,  const u32* __restrict__ wq,
    const u32* __restrict__ wk, const u32* __restrict__ wl,
    const u32* __restrict__ bl, const u32* __restrict__ ei,
    int* __restrict__ flags)
{
    const int lane = threadIdx.x;
    int b;
    b = fp32_vote(x,  256, lane); if (lane == 0) flags[0] = (b > 64);
    b = fp32_vote(wq, 128, lane); if (lane == 0) flags[1] = (b > 32);
    b = fp32_vote(wk, 128, lane); if (lane == 0) flags[2] = (b > 32);
    b = fp32_vote(wl, 256, lane); if (lane == 0) flags[3] = (b > 64);
    b = fp32_vote(bl,  64, lane); if (lane == 0) flags[4] = (b > 16);
    int z = 0;
    for (int i = lane; i < 256; i += 64)
        if (ei[2 * i + 1] == 0) ++z;
    #pragma unroll
    for (int off = 32; off > 0; off >>= 1) z += __shfl_down(z, off);
    if (lane == 0) flags[5] = (z > 128);
}

// ---------------------------------------------------------------------------
#define W_TOTAL (512 + 512 + 16384 + 128)
__global__ __launch_bounds__(256) void canon_w_kernel(
    const void* __restrict__ Wq, const void* __restrict__ Wk,
    const void* __restrict__ Wl, const void* __restrict__ bl,
    const int* __restrict__ flags, float* __restrict__ wf)
{
    const int i = blockIdx.x * 256 + threadIdx.x;
    if (i >= W_TOTAL) return;
    const void* src; int j, f;
    if (i < 512)         { src = Wq; j = i;         f = flags[1]; }
    else if (i < 1024)   { src = Wk; j = i - 512;   f = flags[2]; }
    else if (i < 17408)  { src = Wl; j = i - 1024;  f = flags[3]; }
    else                 { src = bl; j = i - 17408; f = flags[4]; }
    wf[i] = fload(src, f, j);
}

// ---------------------------------------------------------------------------
// K1 v2: h_proj (bf16 storage) = x @ Wl^T + bl
// ---------------------------------------------------------------------------
#define PB_NODES 32
__global__ __launch_bounds__(512) void proj_kernel(
    const void* __restrict__ x, const int* __restrict__ flags,
    const float* __restrict__ wf, u16* __restrict__ h_projb)
{
    __shared__ u32  sWT32[64 * DIM];     // 32 KB
    __shared__ float sx[4][DIM];         // 2 KB
    const int t = threadIdx.x;
    const int o = t & 127;               // output dim
    const int g = t >> 7;                // node group 0..3
    const int fx = flags[0];
    const float* Wl = wf + 1024;
    const float* bl = wf + 17408;

    for (int i = t; i < 64 * DIM; i += 512) {
        const int k2 = i >> 7;
        const int oo = i & 127;
        const float w0 = Wl[oo * DIM + 2 * k2];
        const float w1 = Wl[oo * DIM + 2 * k2 + 1];
        sWT32[i] = (u32)f2b(w0) | ((u32)f2b(w1) << 16);
    }
    const float blv = bl[o];

    for (int rep = 0; rep < 8; ++rep) {
        const int n = blockIdx.x * PB_NODES + rep * 4 + g;
        __syncthreads();
        if (n < N_NODES) sx[g][o] = fload(x, fx, n * DIM + o);
        __syncthreads();
        if (n >= N_NODES) continue;
        float acc0 = blv, acc1 = 0.f;
        #pragma unroll 8
        for (int k2 = 0; k2 < 64; ++k2) {
            const u32 w = sWT32[k2 * DIM + o];
            acc0 = fmaf(sx[g][2 * k2],     b2f((u16)(w & 0xffff)), acc0);
            acc1 = fmaf(sx[g][2 * k2 + 1], b2f((u16)(w >> 16)),    acc1);
        }
        h_projb[n * DIM + o] = f2b(acc0 + acc1);
    }
}

// ---------------------------------------------------------------------------
// K2: h_q = x@Wq^T, k_act = leaky(x@Wk^T)   (validated r9/r10)
// ---------------------------------------------------------------------------
__global__ __launch_bounds__(256) void qk_kernel(
    const void* __restrict__ x, const int* __restrict__ flags,
    const float* __restrict__ wf,
    float* __restrict__ h_q, float* __restrict__ k_act)
{
    const int wave = threadIdx.x >> 6, lane = threadIdx.x & 63;
    const int n = blockIdx.x * 4 + wave;
    if (n >= N_NODES) return;
    const int fx = flags[0];
    const float x0 = fload(x, fx, n * DIM + 2 * lane);
    const float x1 = fload(x, fx, n * DIM + 2 * lane + 1);
    #pragma unroll
    for (int h = 0; h < NHEADS; ++h) {
        const float qx = wf[h * DIM + 2 * lane];
        const float qy = wf[h * DIM + 2 * lane + 1];
        const float kx = wf[512 + h * DIM + 2 * lane];
        const float ky = wf[512 + h * DIM + 2 * lane + 1];
        float pq = x0 * qx + x1 * qy;
        float pk = x0 * kx + x1 * ky;
        #pragma unroll
        for (int off = 32; off > 0; off >>= 1) {
            pq += __shfl_down(pq, off);
            pk += __shfl_down(pk, off);
        }
        if (lane == 0) {
            h_q[n * NHEADS + h]   = pq;
            k_act[n * NHEADS + h] = leaky(pk);
        }
    }
}

// ---------------------------------------------------------------------------
// K5 v2: direct fixed-capacity CSR scatter (no hist/scan/offsets).
//   slot = r*CAP + p, p from single atomicAdd on cursor[r].
//   Overflow (p >= CAP, expected never for Poisson(32)): packed (r<<16)|c
//   appended to ovf list -> handled correctly by qagg/attn rare path.
// ---------------------------------------------------------------------------
__global__ __launch_bounds__(256) void csr_kernel(
    const void* __restrict__ ei, const int* __restrict__ flags,
    int* __restrict__ cursor, int* __restrict__ csr_col,
    int* __restrict__ ovf_cnt, u32* __restrict__ ovf)
{
    const int e = blockIdx.x * 256 + threadIdx.x;
    if (e >= N_EDGES) return;
    const int fe = flags[5];
    const int r = eload(ei, fe, e);
    const int c = eload(ei, fe, N_EDGES + e);
    const int p = atomicAdd(&cursor[r], 1);
    if (p < CAP) {
        csr_col[r * CAP + p] = c;
    } else {
        const int i = atomicAdd(ovf_cnt, 1);
        ovf[i] = ((u32)r << 16) | (u32)c;     // both < 65536
    }
}

// ---------------------------------------------------------------------------
// K6 v2: q_agg[n] = sum over incoming edges of h_q[col]  (wave per node)
// ---------------------------------------------------------------------------
__global__ __launch_bounds__(256) void qagg_kernel(
    const int* __restrict__ cursor, const int* __restrict__ csr_col,
    const int* __restrict__ ovf_cnt, const u32* __restrict__ ovf,
    const float* __restrict__ h_q, float* __restrict__ q_agg)
{
    const int wave = threadIdx.x >> 6, lane = threadIdx.x & 63;
    const int n = blockIdx.x * 4 + wave;
    if (n >= N_NODES) return;
    const int deg = cursor[n];
    const int prim = min(deg, CAP);
    const int s0 = n * CAP;
    float a0 = 0.f, a1 = 0.f, a2 = 0.f, a3 = 0.f;
    for (int s = lane; s < prim; s += 64) {
        const int c = csr_col[s0 + s];
        const float4 q = ((const float4*)h_q)[c];
        a0 += q.x; a1 += q.y; a2 += q.z; a3 += q.w;
    }
    if (deg > CAP) {                       // rare-path: scan overflow list
        const int on = *ovf_cnt;
        for (int i = lane; i < on; i += 64) {
            const u32 pk = ovf[i];
            if ((int)(pk >> 16) == n) {
                const float4 q = ((const float4*)h_q)[pk & 0xffffu];
                a0 += q.x; a1 += q.y; a2 += q.z; a3 += q.w;
            }
        }
    }
    #pragma unroll
    for (int off = 32; off > 0; off >>= 1) {
        a0 += __shfl_down(a0, off); a1 += __shfl_down(a1, off);
        a2 += __shfl_down(a2, off); a3 += __shfl_down(a3, off);
    }
    if (lane == 0) ((float4*)q_agg)[n] = make_float4(a0, a1, a2, a3);
}

// ---------------------------------------------------------------------------
// K7 v4: fused online softmax + weighted aggregation -> out fp32
//   CAP=96 <= 128 so the two cached score strides cover the whole primary
//   slab (no generic primary fallback). Overflow edges (deg > CAP, expected
//   never) handled by an exact rare path over the ovf list.
// ---------------------------------------------------------------------------
__global__ __launch_bounds__(256) void attn_kernel(
    const int* __restrict__ cursor, const int* __restrict__ csr_col,
    const int* __restrict__ ovf_cnt, const u32* __restrict__ ovf,
    const float* __restrict__ k_act, const float* __restrict__ q_agg,
    const u16* __restrict__ h_projb, float* __restrict__ out)
{
    const int wave = threadIdx.x >> 6, lane = threadIdx.x & 63;
    const int n = blockIdx.x * 4 + wave;
    if (n >= N_NODES) return;
    const int deg = cursor[n];
    const int prim = min(deg, CAP);
    const int s0 = n * CAP;
    const float4 k4 = ((const float4*)k_act)[n];

    // ---- pass A: online softmax (m, t) per head; cache both strides ----
    float m0 = -1e30f, m1 = -1e30f, m2 = -1e30f, m3 = -1e30f;
    float t0 = 0.f, t1 = 0.f, t2 = 0.f, t3 = 0.f;

    int cA = 0;
    float sA0 = -1e30f, sA1 = -1e30f, sA2 = -1e30f, sA3 = -1e30f;
    if (lane < prim) {
        cA = csr_col[s0 + lane];
        const float4 q = ((const float4*)q_agg)[cA];
        sA0 = k4.x * q.x; sA1 = k4.y * q.y;
        sA2 = k4.z * q.z; sA3 = k4.w * q.w;
        m0 = sA0; t0 = 1.f;  m1 = sA1; t1 = 1.f;   // first update exact
        m2 = sA2; t2 = 1.f;  m3 = sA3; t3 = 1.f;
    }
    int cB = 0;
    float sB0 = -1e30f, sB1 = -1e30f, sB2 = -1e30f, sB3 = -1e30f;
    if (prim > 64 && 64 + lane < prim) {
        cB = csr_col[s0 + 64 + lane];
        const float4 q = ((const float4*)q_agg)[cB];
        sB0 = k4.x * q.x; sB1 = k4.y * q.y;
        sB2 = k4.z * q.z; sB3 = k4.w * q.w;
        float nm;
        nm = fmaxf(m0, sB0); t0 = t0 * __expf(m0 - nm) + __expf(sB0 - nm); m0 = nm;
        nm = fmaxf(m1, sB1); t1 = t1 * __expf(m1 - nm) + __expf(sB1 - nm); m1 = nm;
        nm = fmaxf(m2, sB2); t2 = t2 * __expf(m2 - nm) + __expf(sB2 - nm); m2 = nm;
        nm = fmaxf(m3, sB3); t3 = t3 * __expf(m3 - nm) + __expf(sB3 - nm); m3 = nm;
    }
    const int ovf_n = (deg > CAP) ? *ovf_cnt : 0;
    // rare-path overflow edges contribute to the online softmax
    for (int i = lane; i < ovf_n; i += 64) {
        const u32 pk = ovf[i];
        if ((int)(pk >> 16) != n) continue;
        const float4 q = ((const float4*)q_agg)[pk & 0xffffu];
        float sc, nm;
        sc = k4.x * q.x; nm = fmaxf(m0, sc); t0 = t0 * __expf(m0 - nm) + __expf(sc - nm); m0 = nm;
        sc = k4.y * q.y; nm = fmaxf(m1, sc); t1 = t1 * __expf(m1 - nm) + __expf(sc - nm); m1 = nm;
        sc = k4.z * q.z; nm = fmaxf(m2, sc); t2 = t2 * __expf(m2 - nm) + __expf(sc - nm); m2 = nm;
        sc = k4.w * q.w; nm = fmaxf(m3, sc); t3 = t3 * __expf(m3 - nm) + __expf(sc - nm); m3 = nm;
    }
    #pragma unroll
    for (int off = 32; off > 0; off >>= 1) {
        float om, ot, nm;
        om = __shfl_xor(m0, off); ot = __shfl_xor(t0, off);
        nm = fmaxf(m0, om); t0 = t0 * __expf(m0 - nm) + ot * __expf(om - nm); m0 = nm;
        om = __shfl_xor(m1, off); ot = __shfl_xor(t1, off);
        nm = fmaxf(m1, om); t1 = t1 * __expf(m1 - nm) + ot * __expf(om - nm); m1 = nm;
        om = __shfl_xor(m2, off); ot = __shfl_xor(t2, off);
        nm = fmaxf(m2, om); t2 = t2 * __expf(m2 - nm) + ot * __expf(om - nm); m2 = nm;
        om = __shfl_xor(m3, off); ot = __shfl_xor(t3, off);
        nm = fmaxf(m3, om); t3 = t3 * __expf(m3 - nm) + ot * __expf(om - nm); m3 = nm;
    }
    const float r0 = 0.25f / (t0 + 1e-8f), r1 = 0.25f / (t1 + 1e-8f);
    const float r2 = 0.25f / (t2 + 1e-8f), r3 = 0.25f / (t3 + 1e-8f);

    // ---- pass B: dual-edge broadcast accumulate ----
    const int sub = lane & 31;          // dim group: dims 4*sub .. 4*sub+3
    const int eh  = lane >> 5;          // which edge of the pair this half takes
    float acc0 = 0.f, acc1 = 0.f, acc2 = 0.f, acc3 = 0.f;
    const uint2* hp2 = (const uint2*)h_projb;   // row stride = 32 uint2 (256 B)

    for (int base = 0; base < prim; base += 64) {
        int   c_s;
        float a_s;
        if (base == 0) {               // cached stride 0 (invalid lanes: exp->0)
            c_s = cA;
            a_s = __expf(sA0 - m0) * r0 + __expf(sA1 - m1) * r1
                + __expf(sA2 - m2) * r2 + __expf(sA3 - m3) * r3;
        } else {                       // cached stride 1 (base == 64)
            c_s = cB;
            a_s = __expf(sB0 - m0) * r0 + __expf(sB1 - m1) * r1
                + __expf(sB2 - m2) * r2 + __expf(sB3 - m3) * r3;
        }
        const int cnt = min(64, prim - base);
        #pragma unroll 4
        for (int j = 0; j < cnt; j += 2) {
            // lanes 0-31 take edge j, lanes 32-63 take edge j+1; a==0 pads
            const int   c = __shfl(c_s, j + eh);
            const float a = __shfl(a_s, j + eh);
            const uint2 w = hp2[(size_t)c * 32 + sub];
            acc0 = fmaf(a, bflo(w.x), acc0);
            acc1 = fmaf(a, bfhi(w.x), acc1);
            acc2 = fmaf(a, bflo(w.y), acc2);
            acc3 = fmaf(a, bfhi(w.y), acc3);
        }
    }
    // rare-path overflow edges (deg > CAP): exact recompute + same broadcast
    for (int base = 0; base < ovf_n; base += 64) {
        const int i = base + lane;
        int   c_s = 0;
        float a_s = 0.f;
        if (i < ovf_n) {
            const u32 pk = ovf[i];
            if ((int)(pk >> 16) == n) {
                c_s = (int)(pk & 0xffffu);
                const float4 q = ((const float4*)q_agg)[c_s];
                a_s = __expf(k4.x * q.x - m0) * r0 + __expf(k4.y * q.y - m1) * r1
                    + __expf(k4.z * q.z - m2) * r2 + __expf(k4.w * q.w - m3) * r3;
            }
        }
        const int cnt = min(64, ovf_n - base);
        for (int j = 0; j < cnt; j += 2) {
            const int   jj = j + eh;
            const int   c = __shfl(c_s, jj);
            const float a = (jj < cnt) ? __shfl(a_s, jj) : 0.f;
            const uint2 w = hp2[(size_t)c * 32 + sub];
            acc0 = fmaf(a, bflo(w.x), acc0);
            acc1 = fmaf(a, bfhi(w.x), acc1);
            acc2 = fmaf(a, bflo(w.y), acc2);
            acc3 = fmaf(a, bfhi(w.y), acc3);
        }
    }
    // combine the two halves, then 32-lane float4 store
    acc0 += __shfl_down(acc0, 32);
    acc1 += __shfl_down(acc1, 32);
    acc2 += __shfl_down(acc2, 32);
    acc3 += __shfl_down(acc3, 32);
    if (eh == 0)
        ((float4*)out)[(size_t)n * 32 + sub] =
            make_float4(leaky(acc0), leaky(acc1), leaky(acc2), leaky(acc3));
}

// ---------------------------------------------------------------------------
extern "C" void kernel_launch(void* const* d_in, const int* in_sizes, int n_in,
                              void* d_out, int out_size, void* d_ws, size_t ws_size,
                              hipStream_t stream)
{
    const void* x  = d_in[0];
    const void* ei = d_in[1];
    const void* Wq = d_in[2];
    const void* Wk = d_in[3];
    const void* Wl = d_in[4];
    const void* bl = d_in[5];
    float* out = (float*)d_out;   // reference output dtype = float32

    char* ws = (char*)d_ws;
    size_t off = 0;
    auto alloc = [&](size_t bytes) -> size_t {
        off = (off + 255) & ~(size_t)255;
        size_t o = off; off += bytes; return o;
    };
    const size_t o_flag  = alloc(256);
    const size_t o_wf    = alloc((size_t)W_TOTAL * sizeof(float));
    const size_t o_hq    = alloc((size_t)N_NODES * NHEADS * sizeof(float));
    const size_t o_kact  = alloc((size_t)N_NODES * NHEADS * sizeof(float));
    const size_t o_qagg  = alloc((size_t)N_NODES * NHEADS * sizeof(float));
    const size_t o_hproj = alloc((size_t)N_NODES * DIM * sizeof(u16));
    const size_t o_cur   = alloc((size_t)N_NODES * sizeof(int));   // zeroed
    const size_t o_ovfc  = alloc(256);                             // zeroed
    const size_t o_csr   = alloc((size_t)N_NODES * CAP * sizeof(int)); // 19.2 MB
    const size_t o_ovf   = alloc((size_t)N_EDGES * sizeof(u32));       // 6.4 MB
    (void)ws_size;   // ~41 MB total, ws_size proven >= 45.9 MB in r7

    int*   flags   = (int*)(ws + o_flag);
    float* wf      = (float*)(ws + o_wf);
    float* h_q     = (float*)(ws + o_hq);
    float* k_act   = (float*)(ws + o_kact);
    float* q_agg   = (float*)(ws + o_qagg);
    u16*   h_projb = (u16*)(ws + o_hproj);
    int*   cursor  = (int*)(ws + o_cur);
    int*   ovf_cnt = (int*)(ws + o_ovfc);
    int*   csr_col = (int*)(ws + o_csr);
    u32*   ovf     = (u32*)(ws + o_ovf);

    // zero cursor + overflow counter in one memset (contiguous regions)
    hipMemsetAsync(ws + o_cur, 0, (o_ovfc - o_cur) + 256, stream);

    const int EB = (N_EDGES + 255) / 256;
    detect_all_kernel<<<1, 64, 0, stream>>>(
        (const u32*)x, (const u32*)Wq, (const u32*)Wk, (const u32*)Wl,
        (const u32*)bl, (const u32*)ei, flags);
    canon_w_kernel<<<(W_TOTAL + 255) / 256, 256, 0, stream>>>(Wq, Wk, Wl, bl, flags, wf);
    proj_kernel<<<(N_NODES + PB_NODES - 1) / PB_NODES, 512, 0, stream>>>(
        x, flags, wf, h_projb);
    qk_kernel<<<N_NODES / 4, 256, 0, stream>>>(x, flags, wf, h_q, k_act);
    csr_kernel<<<EB, 256, 0, stream>>>(ei, flags, cursor, csr_col, ovf_cnt, ovf);
    qagg_kernel<<<N_NODES / 4, 256, 0, stream>>>(cursor, csr_col, ovf_cnt, ovf,
                                                 h_q, q_agg);
    attn_kernel<<<N_NODES / 4, 256, 0, stream>>>(cursor, csr_col, ovf_cnt, ovf,
                                                 k_act, q_agg, h_projb, out);
}

// Round 3
// 364.364 us; speedup vs baseline: 1.5262x; 1.1159x over previous
//
#include <hip/hip_runtime.h>
#include <cstdint>
#include <cstddef>

typedef unsigned short u16;
typedef unsigned int   u32;
typedef long long      i64;

#define N_NODES 50000
#define N_EDGES 1600000
#define DIM     128
#define NHEADS  4
#define NEG_SLOPE 0.2f
#define CAP     64          // per-node slab (max deg ~58 for Binom(1.6M,1/50k); exact ovf path)
#define NSLICE  8
#define SLICE_NODES (N_NODES / NSLICE)   // 6250

__device__ __forceinline__ float b2f(u16 u) {
    union { u32 u; float f; } v; v.u = ((u32)u) << 16; return v.f;
}
__device__ __forceinline__ float bflo(u32 w) {
    union { u32 u; float f; } v; v.u = w << 16; return v.f;
}
__device__ __forceinline__ float bfhi(u32 w) {
    union { u32 u; float f; } v; v.u = w & 0xffff0000u; return v.f;
}
__device__ __forceinline__ u16 f2b(float f) {
    union { float f; u32 u; } v; v.f = f;
    u32 u = v.u;
    u32 r = (u + 0x7fffu + ((u >> 16) & 1u)) >> 16;
    return (u16)r;
}
__device__ __forceinline__ float leaky(float v) {
    return v >= 0.f ? v : NEG_SLOPE * v;
}
// f=1: fp32 storage; f=0: packed bf16
__device__ __forceinline__ float fload(const void* p, int f, int idx) {
    return f ? ((const float*)p)[idx] : b2f(((const u16*)p)[idx]);
}
// edge_index stored (2, E) row-major: elem[e]=row_e, elem[E+e]=col_e
__device__ __forceinline__ int eload(const void* ei, int f64, int idx) {
    return f64 ? (int)((const i64*)ei)[idx] : ((const int*)ei)[idx];
}

// ---------------------------------------------------------------------------
// K0: storage detection. flags: [0]=x [1]=Wq [2]=Wk [3]=Wl [4]=bl [5]=ei-int64
// ---------------------------------------------------------------------------
__device__ __forceinline__ int fp32_vote(const u32* p, int K, int lane) {
    int bad = 0;
    for (int i = lane; i < K; i += 64) {
        const u32 w = p[i];
        const u16 lo = (u16)(w & 0xffff);
        const float v = b2f(lo);
        if (lo == 0 || !(fabsf(v) < 1e4f)) ++bad;
    }
    #pragma unroll
    for (int off = 32; off > 0; off >>= 1) bad += __shfl_down(bad, off);
    return bad;
}

__global__ __launch_bounds__(64) void detect_all_kernel(
    const u32* __restrict__ x,  const u32* __restrict__ wq,
    const u32* __restrict__ wk, const u32* __restrict__ wl,
    const u32* __restrict__ bl, const u32* __restrict__ ei,
    int* __restrict__ flags)
{
    const int lane = threadIdx.x;
    int b;
    b = fp32_vote(x,  256, lane); if (lane == 0) flags[0] = (b > 64);
    b = fp32_vote(wq, 128, lane); if (lane == 0) flags[1] = (b > 32);
    b = fp32_vote(wk, 128, lane); if (lane == 0) flags[2] = (b > 32);
    b = fp32_vote(wl, 256, lane); if (lane == 0) flags[3] = (b > 64);
    b = fp32_vote(bl,  64, lane); if (lane == 0) flags[4] = (b > 16);
    int z = 0;
    for (int i = lane; i < 256; i += 64)
        if (ei[2 * i + 1] == 0) ++z;
    #pragma unroll
    for (int off = 32; off > 0; off >>= 1) z += __shfl_down(z, off);
    if (lane == 0) flags[5] = (z > 128);
}

// ---------------------------------------------------------------------------
#define W_TOTAL (512 + 512 + 16384 + 128)
__global__ __launch_bounds__(256) void canon_w_kernel(
    const void* __restrict__ Wq, const void* __restrict__ Wk,
    const void* __restrict__ Wl, const void* __restrict__ bl,
    const int* __restrict__ flags, float* __restrict__ wf)
{
    const int i = blockIdx.x * 256 + threadIdx.x;
    if (i >= W_TOTAL) return;
    const void* src; int j, f;
    if (i < 512)         { src = Wq; j = i;         f = flags[1]; }
    else if (i < 1024)   { src = Wk; j = i - 512;   f = flags[2]; }
    else if (i < 17408)  { src = Wl; j = i - 1024;  f = flags[3]; }
    else                 { src = bl; j = i - 17408; f = flags[4]; }
    wf[i] = fload(src, f, j);
}

// ---------------------------------------------------------------------------
// K1 v2: h_proj (bf16 storage) = x @ Wl^T + bl
// ---------------------------------------------------------------------------
#define PB_NODES 32
__global__ __launch_bounds__(512) void proj_kernel(
    const void* __restrict__ x, const int* __restrict__ flags,
    const float* __restrict__ wf, u16* __restrict__ h_projb)
{
    __shared__ u32  sWT32[64 * DIM];     // 32 KB
    __shared__ float sx[4][DIM];         // 2 KB
    const int t = threadIdx.x;
    const int o = t & 127;               // output dim
    const int g = t >> 7;                // node group 0..3
    const int fx = flags[0];
    const float* Wl = wf + 1024;
    const float* bl = wf + 17408;

    for (int i = t; i < 64 * DIM; i += 512) {
        const int k2 = i >> 7;
        const int oo = i & 127;
        const float w0 = Wl[oo * DIM + 2 * k2];
        const float w1 = Wl[oo * DIM + 2 * k2 + 1];
        sWT32[i] = (u32)f2b(w0) | ((u32)f2b(w1) << 16);
    }
    const float blv = bl[o];

    for (int rep = 0; rep < 8; ++rep) {
        const int n = blockIdx.x * PB_NODES + rep * 4 + g;
        __syncthreads();
        if (n < N_NODES) sx[g][o] = fload(x, fx, n * DIM + o);
        __syncthreads();
        if (n >= N_NODES) continue;
        float acc0 = blv, acc1 = 0.f;
        #pragma unroll 8
        for (int k2 = 0; k2 < 64; ++k2) {
            const u32 w = sWT32[k2 * DIM + o];
            acc0 = fmaf(sx[g][2 * k2],     b2f((u16)(w & 0xffff)), acc0);
            acc1 = fmaf(sx[g][2 * k2 + 1], b2f((u16)(w >> 16)),    acc1);
        }
        h_projb[n * DIM + o] = f2b(acc0 + acc1);
    }
}

// ---------------------------------------------------------------------------
// K2: h_q = x@Wq^T, k_act = leaky(x@Wk^T)
// ---------------------------------------------------------------------------
__global__ __launch_bounds__(256) void qk_kernel(
    const void* __restrict__ x, const int* __restrict__ flags,
    const float* __restrict__ wf,
    float* __restrict__ h_q, float* __restrict__ k_act)
{
    const int wave = threadIdx.x >> 6, lane = threadIdx.x & 63;
    const int n = blockIdx.x * 4 + wave;
    if (n >= N_NODES) return;
    const int fx = flags[0];
    const float x0 = fload(x, fx, n * DIM + 2 * lane);
    const float x1 = fload(x, fx, n * DIM + 2 * lane + 1);
    #pragma unroll
    for (int h = 0; h < NHEADS; ++h) {
        const float qx = wf[h * DIM + 2 * lane];
        const float qy = wf[h * DIM + 2 * lane + 1];
        const float kx = wf[512 + h * DIM + 2 * lane];
        const float ky = wf[512 + h * DIM + 2 * lane + 1];
        float pq = x0 * qx + x1 * qy;
        float pk = x0 * kx + x1 * ky;
        #pragma unroll
        for (int off = 32; off > 0; off >>= 1) {
            pq += __shfl_down(pq, off);
            pk += __shfl_down(pk, off);
        }
        if (lane == 0) {
            h_q[n * NHEADS + h]   = pq;
            k_act[n * NHEADS + h] = leaky(pk);
        }
    }
}

// ---------------------------------------------------------------------------
// K5 v3: destination-sliced fixed-capacity CSR scatter.
//   slice = blockIdx & 7 (round-robin block->XCD heuristic): all writes to
//   a node's slab line + its cursor come from ONE XCD -> lines stay L2-
//   resident instead of ping-ponging between non-coherent per-XCD L2s
//   (r2 counters: WRITE_SIZE 99 MB = 16x writeback of 6.4 MB dirty data).
//   Cost: each edge chunk is read 8x, but edges are L3-resident (~4 us).
// ---------------------------------------------------------------------------
__global__ __launch_bounds__(256) void csr_kernel(
    const void* __restrict__ ei, const int* __restrict__ flags,
    int* __restrict__ cursor, int* __restrict__ csr_col,
    int* __restrict__ ovf_cnt, u32* __restrict__ ovf)
{
    const int slice  = blockIdx.x & (NSLICE - 1);
    const int chunk  = blockIdx.x >> 3;
    const int nchunk = gridDim.x >> 3;
    const int per    = (N_EDGES + nchunk - 1) / nchunk;
    const int e0     = chunk * per;
    const int e1     = min(e0 + per, N_EDGES);
    const int lo     = slice * SLICE_NODES;
    const int hi     = lo + SLICE_NODES;
    const int fe     = flags[5];
    for (int e = e0 + threadIdx.x; e < e1; e += 256) {
        const int r = eload(ei, fe, e);
        if (r < lo || r >= hi) continue;
        const int c = eload(ei, fe, N_EDGES + e);
        const int p = atomicAdd(&cursor[r], 1);
        if (p < CAP) {
            csr_col[r * CAP + p] = c;
        } else {
            const int i = atomicAdd(ovf_cnt, 1);
            ovf[i] = ((u32)r << 16) | (u32)c;     // both < 65536
        }
    }
}

// ---------------------------------------------------------------------------
// K6 v3: q_agg[n] = sum over incoming edges of h_q[col]  (wave per node)
//   CAP=64 -> single stride.
// ---------------------------------------------------------------------------
__global__ __launch_bounds__(256) void qagg_kernel(
    const int* __restrict__ cursor, const int* __restrict__ csr_col,
    const int* __restrict__ ovf_cnt, const u32* __restrict__ ovf,
    const float* __restrict__ h_q, float* __restrict__ q_agg)
{
    const int wave = threadIdx.x >> 6, lane = threadIdx.x & 63;
    const int n = blockIdx.x * 4 + wave;
    if (n >= N_NODES) return;
    const int deg = cursor[n];
    const int prim = min(deg, CAP);
    float a0 = 0.f, a1 = 0.f, a2 = 0.f, a3 = 0.f;
    if (lane < prim) {
        const int c = csr_col[n * CAP + lane];
        const float4 q = ((const float4*)h_q)[c];
        a0 = q.x; a1 = q.y; a2 = q.z; a3 = q.w;
    }
    if (deg > CAP) {                       // rare-path: scan overflow list
        const int on = *ovf_cnt;
        for (int i = lane; i < on; i += 64) {
            const u32 pk = ovf[i];
            if ((int)(pk >> 16) == n) {
                const float4 q = ((const float4*)h_q)[pk & 0xffffu];
                a0 += q.x; a1 += q.y; a2 += q.z; a3 += q.w;
            }
        }
    }
    #pragma unroll
    for (int off = 32; off > 0; off >>= 1) {
        a0 += __shfl_down(a0, off); a1 += __shfl_down(a1, off);
        a2 += __shfl_down(a2, off); a3 += __shfl_down(a3, off);
    }
    if (lane == 0) ((float4*)q_agg)[n] = make_float4(a0, a1, a2, a3);
}

// ---------------------------------------------------------------------------
// K7 v5: fused online softmax + weighted aggregation -> out fp32
//   CAP=64 -> single cached stride covers the whole primary slab.
//   Overflow edges (deg > CAP, expected ~never) handled exactly.
// ---------------------------------------------------------------------------
__global__ __launch_bounds__(256) void attn_kernel(
    const int* __restrict__ cursor, const int* __restrict__ csr_col,
    const int* __restrict__ ovf_cnt, const u32* __restrict__ ovf,
    const float* __restrict__ k_act, const float* __restrict__ q_agg,
    const u16* __restrict__ h_projb, float* __restrict__ out)
{
    const int wave = threadIdx.x >> 6, lane = threadIdx.x & 63;
    const int n = blockIdx.x * 4 + wave;
    if (n >= N_NODES) return;
    const int deg = cursor[n];
    const int prim = min(deg, CAP);
    const float4 k4 = ((const float4*)k_act)[n];

    // ---- pass A: scores for the single primary stride, online m/t ----
    float m0 = -1e30f, m1 = -1e30f, m2 = -1e30f, m3 = -1e30f;
    float t0 = 0.f, t1 = 0.f, t2 = 0.f, t3 = 0.f;

    int cA = 0;
    float sA0 = -1e30f, sA1 = -1e30f, sA2 = -1e30f, sA3 = -1e30f;
    if (lane < prim) {
        cA = csr_col[n * CAP + lane];
        const float4 q = ((const float4*)q_agg)[cA];
        sA0 = k4.x * q.x; sA1 = k4.y * q.y;
        sA2 = k4.z * q.z; sA3 = k4.w * q.w;
        m0 = sA0; t0 = 1.f;  m1 = sA1; t1 = 1.f;
        m2 = sA2; t2 = 1.f;  m3 = sA3; t3 = 1.f;
    }
    const int ovf_n = (deg > CAP) ? *ovf_cnt : 0;
    for (int i = lane; i < ovf_n; i += 64) {
        const u32 pk = ovf[i];
        if ((int)(pk >> 16) != n) continue;
        const float4 q = ((const float4*)q_agg)[pk & 0xffffu];
        float sc, nm;
        sc = k4.x * q.x; nm = fmaxf(m0, sc); t0 = t0 * __expf(m0 - nm) + __expf(sc - nm); m0 = nm;
        sc = k4.y * q.y; nm = fmaxf(m1, sc); t1 = t1 * __expf(m1 - nm) + __expf(sc - nm); m1 = nm;
        sc = k4.z * q.z; nm = fmaxf(m2, sc); t2 = t2 * __expf(m2 - nm) + __expf(sc - nm); m2 = nm;
        sc = k4.w * q.w; nm = fmaxf(m3, sc); t3 = t3 * __expf(m3 - nm) + __expf(sc - nm); m3 = nm;
    }
    #pragma unroll
    for (int off = 32; off > 0; off >>= 1) {
        float om, ot, nm;
        om = __shfl_xor(m0, off); ot = __shfl_xor(t0, off);
        nm = fmaxf(m0, om); t0 = t0 * __expf(m0 - nm) + ot * __expf(om - nm); m0 = nm;
        om = __shfl_xor(m1, off); ot = __shfl_xor(t1, off);
        nm = fmaxf(m1, om); t1 = t1 * __expf(m1 - nm) + ot * __expf(om - nm); m1 = nm;
        om = __shfl_xor(m2, off); ot = __shfl_xor(t2, off);
        nm = fmaxf(m2, om); t2 = t2 * __expf(m2 - nm) + ot * __expf(om - nm); m2 = nm;
        om = __shfl_xor(m3, off); ot = __shfl_xor(t3, off);
        nm = fmaxf(m3, om); t3 = t3 * __expf(m3 - nm) + ot * __expf(om - nm); m3 = nm;
    }
    const float r0 = 0.25f / (t0 + 1e-8f), r1 = 0.25f / (t1 + 1e-8f);
    const float r2 = 0.25f / (t2 + 1e-8f), r3 = 0.25f / (t3 + 1e-8f);

    // ---- pass B: dual-edge broadcast accumulate (single primary stride) ----
    const int sub = lane & 31;          // dim group: dims 4*sub .. 4*sub+3
    const int eh  = lane >> 5;          // which edge of the pair this half takes
    float acc0 = 0.f, acc1 = 0.f, acc2 = 0.f, acc3 = 0.f;
    const uint2* hp2 = (const uint2*)h_projb;   // row stride = 32 uint2 (256 B)

    if (prim > 0) {
        const float a_s = __expf(sA0 - m0) * r0 + __expf(sA1 - m1) * r1
                        + __expf(sA2 - m2) * r2 + __expf(sA3 - m3) * r3;
        #pragma unroll 4
        for (int j = 0; j < prim; j += 2) {
            // lanes 0-31 take edge j, lanes 32-63 take edge j+1; a==0 pads
            const int   c = __shfl(cA, j + eh);
            const float a = __shfl(a_s, j + eh);
            const uint2 w = hp2[(size_t)c * 32 + sub];
            acc0 = fmaf(a, bflo(w.x), acc0);
            acc1 = fmaf(a, bfhi(w.x), acc1);
            acc2 = fmaf(a, bflo(w.y), acc2);
            acc3 = fmaf(a, bfhi(w.y), acc3);
        }
    }
    // rare-path overflow edges (deg > CAP): exact recompute + same broadcast
    for (int base = 0; base < ovf_n; base += 64) {
        const int i = base + lane;
        int   c_s = 0;
        float a_s = 0.f;
        if (i < ovf_n) {
            const u32 pk = ovf[i];
            if ((int)(pk >> 16) == n) {
                c_s = (int)(pk & 0xffffu);
                const float4 q = ((const float4*)q_agg)[c_s];
                a_s = __expf(k4.x * q.x - m0) * r0 + __expf(k4.y * q.y - m1) * r1
                    + __expf(k4.z * q.z - m2) * r2 + __expf(k4.w * q.w - m3) * r3;
            }
        }
        const int cnt = min(64, ovf_n - base);
        for (int j = 0; j < cnt; j += 2) {
            const int   jj = j + eh;
            const int   c = __shfl(c_s, jj);
            const float a = (jj < cnt) ? __shfl(a_s, jj) : 0.f;
            const uint2 w = hp2[(size_t)c * 32 + sub];
            acc0 = fmaf(a, bflo(w.x), acc0);
            acc1 = fmaf(a, bfhi(w.x), acc1);
            acc2 = fmaf(a, bflo(w.y), acc2);
            acc3 = fmaf(a, bfhi(w.y), acc3);
        }
    }
    // combine the two halves, then 32-lane float4 store
    acc0 += __shfl_down(acc0, 32);
    acc1 += __shfl_down(acc1, 32);
    acc2 += __shfl_down(acc2, 32);
    acc3 += __shfl_down(acc3, 32);
    if (eh == 0)
        ((float4*)out)[(size_t)n * 32 + sub] =
            make_float4(leaky(acc0), leaky(acc1), leaky(acc2), leaky(acc3));
}

// ---------------------------------------------------------------------------
extern "C" void kernel_launch(void* const* d_in, const int* in_sizes, int n_in,
                              void* d_out, int out_size, void* d_ws, size_t ws_size,
                              hipStream_t stream)
{
    const void* x  = d_in[0];
    const void* ei = d_in[1];
    const void* Wq = d_in[2];
    const void* Wk = d_in[3];
    const void* Wl = d_in[4];
    const void* bl = d_in[5];
    float* out = (float*)d_out;   // reference output dtype = float32

    char* ws = (char*)d_ws;
    size_t off = 0;
    auto alloc = [&](size_t bytes) -> size_t {
        off = (off + 255) & ~(size_t)255;
        size_t o = off; off += bytes; return o;
    };
    const size_t o_flag  = alloc(256);
    const size_t o_wf    = alloc((size_t)W_TOTAL * sizeof(float));
    const size_t o_hq    = alloc((size_t)N_NODES * NHEADS * sizeof(float));
    const size_t o_kact  = alloc((size_t)N_NODES * NHEADS * sizeof(float));
    const size_t o_qagg  = alloc((size_t)N_NODES * NHEADS * sizeof(float));
    const size_t o_hproj = alloc((size_t)N_NODES * DIM * sizeof(u16));
    const size_t o_cur   = alloc((size_t)N_NODES * sizeof(int));   // zeroed
    const size_t o_ovfc  = alloc(256);                             // zeroed
    const size_t o_csr   = alloc((size_t)N_NODES * CAP * sizeof(int)); // 12.8 MB
    const size_t o_ovf   = alloc((size_t)N_EDGES * sizeof(u32));       // 6.4 MB
    (void)ws_size;   // ~35 MB total, ws_size proven >= 45.9 MB in r7

    int*   flags   = (int*)(ws + o_flag);
    float* wf      = (float*)(ws + o_wf);
    float* h_q     = (float*)(ws + o_hq);
    float* k_act   = (float*)(ws + o_kact);
    float* q_agg   = (float*)(ws + o_qagg);
    u16*   h_projb = (u16*)(ws + o_hproj);
    int*   cursor  = (int*)(ws + o_cur);
    int*   ovf_cnt = (int*)(ws + o_ovfc);
    int*   csr_col = (int*)(ws + o_csr);
    u32*   ovf     = (u32*)(ws + o_ovf);

    // zero cursor + overflow counter in one memset (contiguous regions)
    hipMemsetAsync(ws + o_cur, 0, (o_ovfc - o_cur) + 256, stream);

    detect_all_kernel<<<1, 64, 0, stream>>>(
        (const u32*)x, (const u32*)Wq, (const u32*)Wk, (const u32*)Wl,
        (const u32*)bl, (const u32*)ei, flags);
    canon_w_kernel<<<(W_TOTAL + 255) / 256, 256, 0, stream>>>(Wq, Wk, Wl, bl, flags, wf);
    proj_kernel<<<(N_NODES + PB_NODES - 1) / PB_NODES, 512, 0, stream>>>(
        x, flags, wf, h_projb);
    qk_kernel<<<N_NODES / 4, 256, 0, stream>>>(x, flags, wf, h_q, k_act);
    // 1024 edge-chunks x 8 slices
    csr_kernel<<<1024 * NSLICE, 256, 0, stream>>>(ei, flags, cursor, csr_col,
                                                  ovf_cnt, ovf);
    qagg_kernel<<<N_NODES / 4, 256, 0, stream>>>(cursor, csr_col, ovf_cnt, ovf,
                                                 h_q, q_agg);
    attn_kernel<<<N_NODES / 4, 256, 0, stream>>>(cursor, csr_col, ovf_cnt, ovf,
                                                 k_act, q_agg, h_projb, out);
}

// Round 5
// 294.841 us; speedup vs baseline: 1.8861x; 1.2358x over previous
//
#include <hip/hip_runtime.h>
#include <cstdint>
#include <cstddef>

typedef unsigned short u16;
typedef unsigned int   u32;
typedef long long      i64;

#define N_NODES 50000
#define N_EDGES 1600000
#define DIM     128
#define NHEADS  4
#define NEG_SLOPE 0.2f
#define CAP     64          // per-node slab (max deg ~58 for Binom(1.6M,1/50k); exact ovf path)
#define NSLICE  8
#define SLICE_NODES (N_NODES / NSLICE)   // 6250

typedef __attribute__((ext_vector_type(8))) short bf16x8;
typedef __attribute__((ext_vector_type(4))) float f32x4;

__device__ __forceinline__ float b2f(u16 u) {
    union { u32 u; float f; } v; v.u = ((u32)u) << 16; return v.f;
}
__device__ __forceinline__ float bflo(u32 w) {
    union { u32 u; float f; } v; v.u = w << 16; return v.f;
}
__device__ __forceinline__ float bfhi(u32 w) {
    union { u32 u; float f; } v; v.u = w & 0xffff0000u; return v.f;
}
__device__ __forceinline__ u16 f2b(float f) {
    union { float f; u32 u; } v; v.f = f;
    u32 u = v.u;
    u32 r = (u + 0x7fffu + ((u >> 16) & 1u)) >> 16;
    return (u16)r;
}
__device__ __forceinline__ float leaky(float v) {
    return v >= 0.f ? v : NEG_SLOPE * v;
}
// f=1: fp32 storage; f=0: packed bf16
__device__ __forceinline__ float fload(const void* p, int f, int idx) {
    return f ? ((const float*)p)[idx] : b2f(((const u16*)p)[idx]);
}
// edge_index stored (2, E) row-major: elem[e]=row_e, elem[E+e]=col_e
__device__ __forceinline__ int eload(const void* ei, int f64, int idx) {
    return f64 ? (int)((const i64*)ei)[idx] : ((const int*)ei)[idx];
}

// ---------------------------------------------------------------------------
// K0: storage detection. flags: [0]=x [1]=Wq [2]=Wk [3]=Wl [4]=bl [5]=ei-int64
// ---------------------------------------------------------------------------
__device__ __forceinline__ int fp32_vote(const u32* p, int K, int lane) {
    int bad = 0;
    for (int i = lane; i < K; i += 64) {
        const u32 w = p[i];
        const u16 lo = (u16)(w & 0xffff);
        const float v = b2f(lo);
        if (lo == 0 || !(fabsf(v) < 1e4f)) ++bad;
    }
    #pragma unroll
    for (int off = 32; off > 0; off >>= 1) bad += __shfl_down(bad, off);
    return bad;
}

__global__ __launch_bounds__(64) void detect_all_kernel(
    const u32* __restrict__ x,  const u32* __restrict__ wq,
    const u32* __restrict__ wk, const u32* __restrict__ wl,
    const u32* __restrict__ bl, const u32* __restrict__ ei,
    int* __restrict__ flags)
{
    const int lane = threadIdx.x;
    int b;
    b = fp32_vote(x,  256, lane); if (lane == 0) flags[0] = (b > 64);
    b = fp32_vote(wq, 128, lane); if (lane == 0) flags[1] = (b > 32);
    b = fp32_vote(wk, 128, lane); if (lane == 0) flags[2] = (b > 32);
    b = fp32_vote(wl, 256, lane); if (lane == 0) flags[3] = (b > 64);
    b = fp32_vote(bl,  64, lane); if (lane == 0) flags[4] = (b > 16);
    int z = 0;
    for (int i = lane; i < 256; i += 64)
        if (ei[2 * i + 1] == 0) ++z;
    #pragma unroll
    for (int off = 32; off > 0; off >>= 1) z += __shfl_down(z, off);
    if (lane == 0) flags[5] = (z > 128);
}

// ---------------------------------------------------------------------------
#define W_TOTAL (512 + 512 + 16384 + 128)
__global__ __launch_bounds__(256) void canon_w_kernel(
    const void* __restrict__ Wq, const void* __restrict__ Wk,
    const void* __restrict__ Wl, const void* __restrict__ bl,
    const int* __restrict__ flags, float* __restrict__ wf)
{
    const int i = blockIdx.x * 256 + threadIdx.x;
    if (i >= W_TOTAL) return;
    const void* src; int j, f;
    if (i < 512)         { src = Wq; j = i;         f = flags[1]; }
    else if (i < 1024)   { src = Wk; j = i - 512;   f = flags[2]; }
    else if (i < 17408)  { src = Wl; j = i - 1024;  f = flags[3]; }
    else                 { src = bl; j = i - 17408; f = flags[4]; }
    wf[i] = fload(src, f, j);
}

// ---------------------------------------------------------------------------
// K1 v3 (MFMA): h_all = x @ [Wl; Wq; Wk]^T  in one bf16 GEMM.
//   Output cols 0-127 -> h_projb (+bias, bf16 store), 128-131 -> h_q (fp32),
//   132-135 -> k_act = leaky (fp32). Absorbs the old qk_kernel.
//   B staged in LDS bf16 [160][128] with (row&7) XOR-swizzle (G4) so the
//   per-lane 16B b-fragments read via ds_read_b128 conflict-free.
//   Tiles: 0-7 = Wl(hi), 8 = Wq/Wk(hi), 9 = Wq/Wk(lo) -> accum into acc[8]
//   (keeps q/k at ~fp32 accuracy since scores feed exp()).
//   fx=1 (fp32 x): x split into bf16 hi+lo, second MFMA chain adds the lo
//   term; fx=0 (bf16 x): hi path is exact, lo skipped.
//   MFMA layout (16x16x32): A[row=l&15][k=(l>>4)*8+i], B[k][col=l&15],
//   D[row=(l>>4)*4+j][col=l&15].
// ---------------------------------------------------------------------------
__global__ __launch_bounds__(256) void proj_kernel(
    const void* __restrict__ x, const int* __restrict__ flags,
    const float* __restrict__ wf, u16* __restrict__ h_projb,
    float* __restrict__ h_q, float* __restrict__ k_act)
{
    __shared__ u16 sB[160 * 128];        // 40 KB
    const int t  = threadIdx.x;
    const int w  = t >> 6;
    const int l  = t & 63;
    const int lr = l & 15;               // row/col within 16-tile
    const int lg = l >> 4;               // k-group / m-group
    const int Mb = blockIdx.x * 64 + w * 16;
    const float* Wl = wf + 1024;
    const float* Wq = wf;
    const float* Wk = wf + 512;
    const float* bl = wf + 17408;

    // ---- stage B (bf16, swizzled) ----
    for (int i = t; i < 160 * 128; i += 256) {
        const int row = i >> 7;
        const int col = i & 127;
        float v;
        if (row < 128)      v = Wl[row * 128 + col];
        else if (row < 132) v = Wq[(row - 128) * 128 + col];
        else if (row < 136) v = Wk[(row - 132) * 128 + col];
        else if (row < 144) v = 0.f;
        else if (row < 148) { const float ww = Wq[(row - 144) * 128 + col]; v = ww - b2f(f2b(ww)); }
        else if (row < 152) { const float ww = Wk[(row - 148) * 128 + col]; v = ww - b2f(f2b(ww)); }
        else                v = 0.f;
        sB[row * 128 + (col ^ ((row & 7) << 3))] = f2b(v);
    }
    __syncthreads();

    const int fx = flags[0];
    f32x4 acc[9];
    #pragma unroll
    for (int tt = 0; tt < 8; ++tt) {
        const float bias = bl[tt * 16 + lr];
        acc[tt][0] = bias; acc[tt][1] = bias; acc[tt][2] = bias; acc[tt][3] = bias;
    }
    acc[8][0] = 0.f; acc[8][1] = 0.f; acc[8][2] = 0.f; acc[8][3] = 0.f;

    const int arow = min(Mb + lr, N_NODES - 1);

    #pragma unroll
    for (int kk = 0; kk < 4; ++kk) {
        const int kbase = kk * 32 + lg * 8;
        bf16x8 ahi, alo;
        if (fx == 0) {
            ahi = *(const bf16x8*)((const u16*)x + (size_t)arow * 128 + kbase);
            #pragma unroll
            for (int i = 0; i < 8; ++i) alo[i] = 0;
        } else {
            const float* xf = (const float*)x + (size_t)arow * 128 + kbase;
            const float4 v0 = *(const float4*)xf;
            const float4 v1 = *(const float4*)(xf + 4);
            const float vv[8] = {v0.x, v0.y, v0.z, v0.w, v1.x, v1.y, v1.z, v1.w};
            #pragma unroll
            for (int i = 0; i < 8; ++i) {
                const u16 h = f2b(vv[i]);
                ahi[i] = (short)h;
                alo[i] = (short)f2b(vv[i] - b2f(h));
            }
        }
        #pragma unroll
        for (int tt = 0; tt < 9; ++tt) {
            const int row = tt * 16 + lr;
            const bf16x8 b = *(const bf16x8*)&sB[row * 128 + (kbase ^ ((row & 7) << 3))];
            acc[tt] = __builtin_amdgcn_mfma_f32_16x16x32_bf16(ahi, b, acc[tt], 0, 0, 0);
            if (fx)
                acc[tt] = __builtin_amdgcn_mfma_f32_16x16x32_bf16(alo, b, acc[tt], 0, 0, 0);
        }
        {   // qk lo-tile (rows 144-159) accumulates into acc[8]
            const int row = 144 + lr;
            const bf16x8 b9 = *(const bf16x8*)&sB[row * 128 + (kbase ^ ((row & 7) << 3))];
            acc[8] = __builtin_amdgcn_mfma_f32_16x16x32_bf16(ahi, b9, acc[8], 0, 0, 0);
        }
    }

    // ---- epilogue ----
    #pragma unroll
    for (int tt = 0; tt < 8; ++tt) {
        const int o = tt * 16 + lr;
        #pragma unroll
        for (int j = 0; j < 4; ++j) {
            const int n = Mb + lg * 4 + j;
            if (n < N_NODES) h_projb[(size_t)n * 128 + o] = f2b(acc[tt][j]);
        }
    }
    #pragma unroll
    for (int j = 0; j < 4; ++j) {
        const int n = Mb + lg * 4 + j;
        if (n < N_NODES) {
            if (lr < 4)      h_q[n * 4 + lr] = acc[8][j];
            else if (lr < 8) k_act[n * 4 + (lr - 4)] = leaky(acc[8][j]);
        }
    }
}

// ---------------------------------------------------------------------------
// K5 v3: destination-sliced fixed-capacity CSR scatter (validated r3).
// ---------------------------------------------------------------------------
__global__ __launch_bounds__(256) void csr_kernel(
    const void* __restrict__ ei, const int* __restrict__ flags,
    int* __restrict__ cursor, int* __restrict__ csr_col,
    int* __restrict__ ovf_cnt, u32* __restrict__ ovf)
{
    const int slice  = blockIdx.x & (NSLICE - 1);
    const int chunk  = blockIdx.x >> 3;
    const int nchunk = gridDim.x >> 3;
    const int per    = (N_EDGES + nchunk - 1) / nchunk;
    const int e0     = chunk * per;
    const int e1     = min(e0 + per, N_EDGES);
    const int lo     = slice * SLICE_NODES;
    const int hi     = lo + SLICE_NODES;
    const int fe     = flags[5];
    for (int e = e0 + threadIdx.x; e < e1; e += 256) {
        const int r = eload(ei, fe, e);
        if (r < lo || r >= hi) continue;
        const int c = eload(ei, fe, N_EDGES + e);
        const int p = atomicAdd(&cursor[r], 1);
        if (p < CAP) {
            csr_col[r * CAP + p] = c;
        } else {
            const int i = atomicAdd(ovf_cnt, 1);
            ovf[i] = ((u32)r << 16) | (u32)c;     // both < 65536
        }
    }
}

// ---------------------------------------------------------------------------
// K6 v3: q_agg[n] = sum over incoming edges of h_q[col]  (wave per node)
// ---------------------------------------------------------------------------
__global__ __launch_bounds__(256) void qagg_kernel(
    const int* __restrict__ cursor, const int* __restrict__ csr_col,
    const int* __restrict__ ovf_cnt, const u32* __restrict__ ovf,
    const float* __restrict__ h_q, float* __restrict__ q_agg)
{
    const int wave = threadIdx.x >> 6, lane = threadIdx.x & 63;
    const int n = blockIdx.x * 4 + wave;
    if (n >= N_NODES) return;
    const int deg = cursor[n];
    const int prim = min(deg, CAP);
    float a0 = 0.f, a1 = 0.f, a2 = 0.f, a3 = 0.f;
    if (lane < prim) {
        const int c = csr_col[n * CAP + lane];
        const float4 q = ((const float4*)h_q)[c];
        a0 = q.x; a1 = q.y; a2 = q.z; a3 = q.w;
    }
    if (deg > CAP) {                       // rare-path: scan overflow list
        const int on = *ovf_cnt;
        for (int i = lane; i < on; i += 64) {
            const u32 pk = ovf[i];
            if ((int)(pk >> 16) == n) {
                const float4 q = ((const float4*)h_q)[pk & 0xffffu];
                a0 += q.x; a1 += q.y; a2 += q.z; a3 += q.w;
            }
        }
    }
    #pragma unroll
    for (int off = 32; off > 0; off >>= 1) {
        a0 += __shfl_down(a0, off); a1 += __shfl_down(a1, off);
        a2 += __shfl_down(a2, off); a3 += __shfl_down(a3, off);
    }
    if (lane == 0) ((float4*)q_agg)[n] = make_float4(a0, a1, a2, a3);
}

// ---------------------------------------------------------------------------
// K7 v5: fused online softmax + weighted aggregation -> out fp32 (validated r3)
// ---------------------------------------------------------------------------
__global__ __launch_bounds__(256) void attn_kernel(
    const int* __restrict__ cursor, const int* __restrict__ csr_col,
    const int* __restrict__ ovf_cnt, const u32* __restrict__ ovf,
    const float* __restrict__ k_act, const float* __restrict__ q_agg,
    const u16* __restrict__ h_projb, float* __restrict__ out)
{
    const int wave = threadIdx.x >> 6, lane = threadIdx.x & 63;
    const int n = blockIdx.x * 4 + wave;
    if (n >= N_NODES) return;
    const int deg = cursor[n];
    const int prim = min(deg, CAP);
    const float4 k4 = ((const float4*)k_act)[n];

    // ---- pass A: scores for the single primary stride, online m/t ----
    float m0 = -1e30f, m1 = -1e30f, m2 = -1e30f, m3 = -1e30f;
    float t0 = 0.f, t1 = 0.f, t2 = 0.f, t3 = 0.f;

    int cA = 0;
    float sA0 = -1e30f, sA1 = -1e30f, sA2 = -1e30f, sA3 = -1e30f;
    if (lane < prim) {
        cA = csr_col[n * CAP + lane];
        const float4 q = ((const float4*)q_agg)[cA];
        sA0 = k4.x * q.x; sA1 = k4.y * q.y;
        sA2 = k4.z * q.z; sA3 = k4.w * q.w;
        m0 = sA0; t0 = 1.f;  m1 = sA1; t1 = 1.f;
        m2 = sA2; t2 = 1.f;  m3 = sA3; t3 = 1.f;
    }
    const int ovf_n = (deg > CAP) ? *ovf_cnt : 0;
    for (int i = lane; i < ovf_n; i += 64) {
        const u32 pk = ovf[i];
        if ((int)(pk >> 16) != n) continue;
        const float4 q = ((const float4*)q_agg)[pk & 0xffffu];
        float sc, nm;
        sc = k4.x * q.x; nm = fmaxf(m0, sc); t0 = t0 * __expf(m0 - nm) + __expf(sc - nm); m0 = nm;
        sc = k4.y * q.y; nm = fmaxf(m1, sc); t1 = t1 * __expf(m1 - nm) + __expf(sc - nm); m1 = nm;
        sc = k4.z * q.z; nm = fmaxf(m2, sc); t2 = t2 * __expf(m2 - nm) + __expf(sc - nm); m2 = nm;
        sc = k4.w * q.w; nm = fmaxf(m3, sc); t3 = t3 * __expf(m3 - nm) + __expf(sc - nm); m3 = nm;
    }
    #pragma unroll
    for (int off = 32; off > 0; off >>= 1) {
        float om, ot, nm;
        om = __shfl_xor(m0, off); ot = __shfl_xor(t0, off);
        nm = fmaxf(m0, om); t0 = t0 * __expf(m0 - nm) + ot * __expf(om - nm); m0 = nm;
        om = __shfl_xor(m1, off); ot = __shfl_xor(t1, off);
        nm = fmaxf(m1, om); t1 = t1 * __expf(m1 - nm) + ot * __expf(om - nm); m1 = nm;
        om = __shfl_xor(m2, off); ot = __shfl_xor(t2, off);
        nm = fmaxf(m2, om); t2 = t2 * __expf(m2 - nm) + ot * __expf(om - nm); m2 = nm;
        om = __shfl_xor(m3, off); ot = __shfl_xor(t3, off);
        nm = fmaxf(m3, om); t3 = t3 * __expf(m3 - nm) + ot * __expf(om - nm); m3 = nm;
    }
    const float r0 = 0.25f / (t0 + 1e-8f), r1 = 0.25f / (t1 + 1e-8f);
    const float r2 = 0.25f / (t2 + 1e-8f), r3 = 0.25f / (t3 + 1e-8f);

    // ---- pass B: dual-edge broadcast accumulate (single primary stride) ----
    const int sub = lane & 31;          // dim group: dims 4*sub .. 4*sub+3
    const int eh  = lane >> 5;          // which edge of the pair this half takes
    float acc0 = 0.f, acc1 = 0.f, acc2 = 0.f, acc3 = 0.f;
    const uint2* hp2 = (const uint2*)h_projb;   // row stride = 32 uint2 (256 B)

    if (prim > 0) {
        const float a_s = __expf(sA0 - m0) * r0 + __expf(sA1 - m1) * r1
                        + __expf(sA2 - m2) * r2 + __expf(sA3 - m3) * r3;
        #pragma unroll 4
        for (int j = 0; j < prim; j += 2) {
            // lanes 0-31 take edge j, lanes 32-63 take edge j+1; a==0 pads
            const int   c = __shfl(cA, j + eh);
            const float a = __shfl(a_s, j + eh);
            const uint2 w = hp2[(size_t)c * 32 + sub];
            acc0 = fmaf(a, bflo(w.x), acc0);
            acc1 = fmaf(a, bfhi(w.x), acc1);
            acc2 = fmaf(a, bflo(w.y), acc2);
            acc3 = fmaf(a, bfhi(w.y), acc3);
        }
    }
    // rare-path overflow edges (deg > CAP): exact recompute + same broadcast
    for (int base = 0; base < ovf_n; base += 64) {
        const int i = base + lane;
        int   c_s = 0;
        float a_s = 0.f;
        if (i < ovf_n) {
            const u32 pk = ovf[i];
            if ((int)(pk >> 16) == n) {
                c_s = (int)(pk & 0xffffu);
                const float4 q = ((const float4*)q_agg)[c_s];
                a_s = __expf(k4.x * q.x - m0) * r0 + __expf(k4.y * q.y - m1) * r1
                    + __expf(k4.z * q.z - m2) * r2 + __expf(k4.w * q.w - m3) * r3;
            }
        }
        const int cnt = min(64, ovf_n - base);
        for (int j = 0; j < cnt; j += 2) {
            const int   jj = j + eh;
            const int   c = __shfl(c_s, jj);
            const float a = (jj < cnt) ? __shfl(a_s, jj) : 0.f;
            const uint2 w = hp2[(size_t)c * 32 + sub];
            acc0 = fmaf(a, bflo(w.x), acc0);
            acc1 = fmaf(a, bfhi(w.x), acc1);
            acc2 = fmaf(a, bflo(w.y), acc2);
            acc3 = fmaf(a, bfhi(w.y), acc3);
        }
    }
    // combine the two halves, then 32-lane float4 store
    acc0 += __shfl_down(acc0, 32);
    acc1 += __shfl_down(acc1, 32);
    acc2 += __shfl_down(acc2, 32);
    acc3 += __shfl_down(acc3, 32);
    if (eh == 0)
        ((float4*)out)[(size_t)n * 32 + sub] =
            make_float4(leaky(acc0), leaky(acc1), leaky(acc2), leaky(acc3));
}

// ---------------------------------------------------------------------------
extern "C" void kernel_launch(void* const* d_in, const int* in_sizes, int n_in,
                              void* d_out, int out_size, void* d_ws, size_t ws_size,
                              hipStream_t stream)
{
    const void* x  = d_in[0];
    const void* ei = d_in[1];
    const void* Wq = d_in[2];
    const void* Wk = d_in[3];
    const void* Wl = d_in[4];
    const void* bl = d_in[5];
    float* out = (float*)d_out;   // reference output dtype = float32

    char* ws = (char*)d_ws;
    size_t off = 0;
    auto alloc = [&](size_t bytes) -> size_t {
        off = (off + 255) & ~(size_t)255;
        size_t o = off; off += bytes; return o;
    };
    const size_t o_flag  = alloc(256);
    const size_t o_wf    = alloc((size_t)W_TOTAL * sizeof(float));
    const size_t o_hq    = alloc((size_t)N_NODES * NHEADS * sizeof(float));
    const size_t o_kact  = alloc((size_t)N_NODES * NHEADS * sizeof(float));
    const size_t o_qagg  = alloc((size_t)N_NODES * NHEADS * sizeof(float));
    const size_t o_hproj = alloc((size_t)N_NODES * DIM * sizeof(u16));
    const size_t o_cur   = alloc((size_t)N_NODES * sizeof(int));   // zeroed
    const size_t o_ovfc  = alloc(256);                             // zeroed
    const size_t o_csr   = alloc((size_t)N_NODES * CAP * sizeof(int)); // 12.8 MB
    const size_t o_ovf   = alloc((size_t)N_EDGES * sizeof(u32));       // 6.4 MB
    (void)ws_size;   // ~35 MB total, ws_size proven >= 45.9 MB in r7

    int*   flags   = (int*)(ws + o_flag);
    float* wf      = (float*)(ws + o_wf);
    float* h_q     = (float*)(ws + o_hq);
    float* k_act   = (float*)(ws + o_kact);
    float* q_agg   = (float*)(ws + o_qagg);
    u16*   h_projb = (u16*)(ws + o_hproj);
    int*   cursor  = (int*)(ws + o_cur);
    int*   ovf_cnt = (int*)(ws + o_ovfc);
    int*   csr_col = (int*)(ws + o_csr);
    u32*   ovf     = (u32*)(ws + o_ovf);

    // zero cursor + overflow counter in one memset (contiguous regions)
    hipMemsetAsync(ws + o_cur, 0, (o_ovfc - o_cur) + 256, stream);

    detect_all_kernel<<<1, 64, 0, stream>>>(
        (const u32*)x, (const u32*)Wq, (const u32*)Wk, (const u32*)Wl,
        (const u32*)bl, (const u32*)ei, flags);
    canon_w_kernel<<<(W_TOTAL + 255) / 256, 256, 0, stream>>>(Wq, Wk, Wl, bl, flags, wf);
    // MFMA GEMM: h_proj + h_q + k_act in one kernel (64 rows/block)
    proj_kernel<<<(N_NODES + 63) / 64, 256, 0, stream>>>(
        x, flags, wf, h_projb, h_q, k_act);
    // 1024 edge-chunks x 8 slices
    csr_kernel<<<1024 * NSLICE, 256, 0, stream>>>(ei, flags, cursor, csr_col,
                                                  ovf_cnt, ovf);
    qagg_kernel<<<N_NODES / 4, 256, 0, stream>>>(cursor, csr_col, ovf_cnt, ovf,
                                                 h_q, q_agg);
    attn_kernel<<<N_NODES / 4, 256, 0, stream>>>(cursor, csr_col, ovf_cnt, ovf,
                                                 k_act, q_agg, h_projb, out);
}

// Round 6
// 276.063 us; speedup vs baseline: 2.0144x; 1.0680x over previous
//
#include <hip/hip_runtime.h>
#include <cstdint>
#include <cstddef>

typedef unsigned short u16;
typedef unsigned int   u32;
typedef long long      i64;

#define N_NODES 50000
#define N_EDGES 1600000
#define DIM     128
#define NHEADS  4
#define NEG_SLOPE 0.2f
#define CAP     64          // per-node slab (max deg ~58 for Binom(1.6M,1/50k); exact ovf path)
#define NSLICE  8
#define SLICE_NODES (N_NODES / NSLICE)   // 6250

typedef __attribute__((ext_vector_type(8))) short bf16x8;
typedef __attribute__((ext_vector_type(4))) float f32x4;

__device__ __forceinline__ float b2f(u16 u) {
    union { u32 u; float f; } v; v.u = ((u32)u) << 16; return v.f;
}
__device__ __forceinline__ float bflo(u32 w) {
    union { u32 u; float f; } v; v.u = w << 16; return v.f;
}
__device__ __forceinline__ float bfhi(u32 w) {
    union { u32 u; float f; } v; v.u = w & 0xffff0000u; return v.f;
}
__device__ __forceinline__ u16 f2b(float f) {
    union { float f; u32 u; } v; v.f = f;
    u32 u = v.u;
    u32 r = (u + 0x7fffu + ((u >> 16) & 1u)) >> 16;
    return (u16)r;
}
__device__ __forceinline__ float leaky(float v) {
    return v >= 0.f ? v : NEG_SLOPE * v;
}
// f=1: fp32 storage; f=0: packed bf16
__device__ __forceinline__ float fload(const void* p, int f, int idx) {
    return f ? ((const float*)p)[idx] : b2f(((const u16*)p)[idx]);
}
// edge_index stored (2, E) row-major: elem[e]=row_e, elem[E+e]=col_e
__device__ __forceinline__ int eload(const void* ei, int f64, int idx) {
    return f64 ? (int)((const i64*)ei)[idx] : ((const int*)ei)[idx];
}

// ---------------------------------------------------------------------------
// K0: storage detection. flags: [0]=x [1]=Wq [2]=Wk [3]=Wl [4]=bl [5]=ei-int64
// ---------------------------------------------------------------------------
__device__ __forceinline__ int fp32_vote(const u32* p, int K, int lane) {
    int bad = 0;
    for (int i = lane; i < K; i += 64) {
        const u32 w = p[i];
        const u16 lo = (u16)(w & 0xffff);
        const float v = b2f(lo);
        if (lo == 0 || !(fabsf(v) < 1e4f)) ++bad;
    }
    #pragma unroll
    for (int off = 32; off > 0; off >>= 1) bad += __shfl_down(bad, off);
    return bad;
}

__global__ __launch_bounds__(64) void detect_all_kernel(
    const u32* __restrict__ x,  const u32* __restrict__ wq,
    const u32* __restrict__ wk, const u32* __restrict__ wl,
    const u32* __restrict__ bl, const u32* __restrict__ ei,
    int* __restrict__ flags)
{
    const int lane = threadIdx.x;
    int b;
    b = fp32_vote(x,  256, lane); if (lane == 0) flags[0] = (b > 64);
    b = fp32_vote(wq, 128, lane); if (lane == 0) flags[1] = (b > 32);
    b = fp32_vote(wk, 128, lane); if (lane == 0) flags[2] = (b > 32);
    b = fp32_vote(wl, 256, lane); if (lane == 0) flags[3] = (b > 64);
    b = fp32_vote(bl,  64, lane); if (lane == 0) flags[4] = (b > 16);
    int z = 0;
    for (int i = lane; i < 256; i += 64)
        if (ei[2 * i + 1] == 0) ++z;
    #pragma unroll
    for (int off = 32; off > 0; off >>= 1) z += __shfl_down(z, off);
    if (lane == 0) flags[5] = (z > 128);
}

// ---------------------------------------------------------------------------
#define W_TOTAL (512 + 512 + 16384 + 128)
__global__ __launch_bounds__(256) void canon_w_kernel(
    const void* __restrict__ Wq, const void* __restrict__ Wk,
    const void* __restrict__ Wl, const void* __restrict__ bl,
    const int* __restrict__ flags, float* __restrict__ wf)
{
    const int i = blockIdx.x * 256 + threadIdx.x;
    if (i >= W_TOTAL) return;
    const void* src; int j, f;
    if (i < 512)         { src = Wq; j = i;         f = flags[1]; }
    else if (i < 1024)   { src = Wk; j = i - 512;   f = flags[2]; }
    else if (i < 17408)  { src = Wl; j = i - 1024;  f = flags[3]; }
    else                 { src = bl; j = i - 17408; f = flags[4]; }
    wf[i] = fload(src, f, j);
}

// ---------------------------------------------------------------------------
// K1 v3 (MFMA): h_all = x @ [Wl; Wq; Wk]^T  in one bf16 GEMM (validated r5).
// ---------------------------------------------------------------------------
__global__ __launch_bounds__(256) void proj_kernel(
    const void* __restrict__ x, const int* __restrict__ flags,
    const float* __restrict__ wf, u16* __restrict__ h_projb,
    float* __restrict__ h_q, float* __restrict__ k_act)
{
    __shared__ u16 sB[160 * 128];        // 40 KB
    const int t  = threadIdx.x;
    const int w  = t >> 6;
    const int l  = t & 63;
    const int lr = l & 15;               // row/col within 16-tile
    const int lg = l >> 4;               // k-group / m-group
    const int Mb = blockIdx.x * 64 + w * 16;
    const float* Wl = wf + 1024;
    const float* Wq = wf;
    const float* Wk = wf + 512;
    const float* bl = wf + 17408;

    // ---- stage B (bf16, swizzled) ----
    for (int i = t; i < 160 * 128; i += 256) {
        const int row = i >> 7;
        const int col = i & 127;
        float v;
        if (row < 128)      v = Wl[row * 128 + col];
        else if (row < 132) v = Wq[(row - 128) * 128 + col];
        else if (row < 136) v = Wk[(row - 132) * 128 + col];
        else if (row < 144) v = 0.f;
        else if (row < 148) { const float ww = Wq[(row - 144) * 128 + col]; v = ww - b2f(f2b(ww)); }
        else if (row < 152) { const float ww = Wk[(row - 148) * 128 + col]; v = ww - b2f(f2b(ww)); }
        else                v = 0.f;
        sB[row * 128 + (col ^ ((row & 7) << 3))] = f2b(v);
    }
    __syncthreads();

    const int fx = flags[0];
    f32x4 acc[9];
    #pragma unroll
    for (int tt = 0; tt < 8; ++tt) {
        const float bias = bl[tt * 16 + lr];
        acc[tt][0] = bias; acc[tt][1] = bias; acc[tt][2] = bias; acc[tt][3] = bias;
    }
    acc[8][0] = 0.f; acc[8][1] = 0.f; acc[8][2] = 0.f; acc[8][3] = 0.f;

    const int arow = min(Mb + lr, N_NODES - 1);

    #pragma unroll
    for (int kk = 0; kk < 4; ++kk) {
        const int kbase = kk * 32 + lg * 8;
        bf16x8 ahi, alo;
        if (fx == 0) {
            ahi = *(const bf16x8*)((const u16*)x + (size_t)arow * 128 + kbase);
            #pragma unroll
            for (int i = 0; i < 8; ++i) alo[i] = 0;
        } else {
            const float* xf = (const float*)x + (size_t)arow * 128 + kbase;
            const float4 v0 = *(const float4*)xf;
            const float4 v1 = *(const float4*)(xf + 4);
            const float vv[8] = {v0.x, v0.y, v0.z, v0.w, v1.x, v1.y, v1.z, v1.w};
            #pragma unroll
            for (int i = 0; i < 8; ++i) {
                const u16 h = f2b(vv[i]);
                ahi[i] = (short)h;
                alo[i] = (short)f2b(vv[i] - b2f(h));
            }
        }
        #pragma unroll
        for (int tt = 0; tt < 9; ++tt) {
            const int row = tt * 16 + lr;
            const bf16x8 b = *(const bf16x8*)&sB[row * 128 + (kbase ^ ((row & 7) << 3))];
            acc[tt] = __builtin_amdgcn_mfma_f32_16x16x32_bf16(ahi, b, acc[tt], 0, 0, 0);
            if (fx)
                acc[tt] = __builtin_amdgcn_mfma_f32_16x16x32_bf16(alo, b, acc[tt], 0, 0, 0);
        }
        {   // qk lo-tile (rows 144-159) accumulates into acc[8]
            const int row = 144 + lr;
            const bf16x8 b9 = *(const bf16x8*)&sB[row * 128 + (kbase ^ ((row & 7) << 3))];
            acc[8] = __builtin_amdgcn_mfma_f32_16x16x32_bf16(ahi, b9, acc[8], 0, 0, 0);
        }
    }

    // ---- epilogue ----
    #pragma unroll
    for (int tt = 0; tt < 8; ++tt) {
        const int o = tt * 16 + lr;
        #pragma unroll
        for (int j = 0; j < 4; ++j) {
            const int n = Mb + lg * 4 + j;
            if (n < N_NODES) h_projb[(size_t)n * 128 + o] = f2b(acc[tt][j]);
        }
    }
    #pragma unroll
    for (int j = 0; j < 4; ++j) {
        const int n = Mb + lg * 4 + j;
        if (n < N_NODES) {
            if (lr < 4)      h_q[n * 4 + lr] = acc[8][j];
            else if (lr < 8) k_act[n * 4 + (lr - 4)] = leaky(acc[8][j]);
        }
    }
}

// ---------------------------------------------------------------------------
// K5 v3: destination-sliced fixed-capacity CSR scatter (validated r3).
// ---------------------------------------------------------------------------
__global__ __launch_bounds__(256) void csr_kernel(
    const void* __restrict__ ei, const int* __restrict__ flags,
    int* __restrict__ cursor, int* __restrict__ csr_col,
    int* __restrict__ ovf_cnt, u32* __restrict__ ovf)
{
    const int slice  = blockIdx.x & (NSLICE - 1);
    const int chunk  = blockIdx.x >> 3;
    const int nchunk = gridDim.x >> 3;
    const int per    = (N_EDGES + nchunk - 1) / nchunk;
    const int e0     = chunk * per;
    const int e1     = min(e0 + per, N_EDGES);
    const int lo     = slice * SLICE_NODES;
    const int hi     = lo + SLICE_NODES;
    const int fe     = flags[5];
    for (int e = e0 + threadIdx.x; e < e1; e += 256) {
        const int r = eload(ei, fe, e);
        if (r < lo || r >= hi) continue;
        const int c = eload(ei, fe, N_EDGES + e);
        const int p = atomicAdd(&cursor[r], 1);
        if (p < CAP) {
            csr_col[r * CAP + p] = c;
        } else {
            const int i = atomicAdd(ovf_cnt, 1);
            ovf[i] = ((u32)r << 16) | (u32)c;     // both < 65536
        }
    }
}

// ---------------------------------------------------------------------------
// K6 v3: q_agg[n] = sum over incoming edges of h_q[col]  (wave per node)
// ---------------------------------------------------------------------------
__global__ __launch_bounds__(256) void qagg_kernel(
    const int* __restrict__ cursor, const int* __restrict__ csr_col,
    const int* __restrict__ ovf_cnt, const u32* __restrict__ ovf,
    const float* __restrict__ h_q, float* __restrict__ q_agg)
{
    const int wave = threadIdx.x >> 6, lane = threadIdx.x & 63;
    const int n = blockIdx.x * 4 + wave;
    if (n >= N_NODES) return;
    const int deg = cursor[n];
    const int prim = min(deg, CAP);
    float a0 = 0.f, a1 = 0.f, a2 = 0.f, a3 = 0.f;
    if (lane < prim) {
        const int c = csr_col[n * CAP + lane];
        const float4 q = ((const float4*)h_q)[c];
        a0 = q.x; a1 = q.y; a2 = q.z; a3 = q.w;
    }
    if (deg > CAP) {                       // rare-path: scan overflow list
        const int on = *ovf_cnt;
        for (int i = lane; i < on; i += 64) {
            const u32 pk = ovf[i];
            if ((int)(pk >> 16) == n) {
                const float4 q = ((const float4*)h_q)[pk & 0xffffu];
                a0 += q.x; a1 += q.y; a2 += q.z; a3 += q.w;
            }
        }
    }
    #pragma unroll
    for (int off = 32; off > 0; off >>= 1) {
        a0 += __shfl_down(a0, off); a1 += __shfl_down(a1, off);
        a2 += __shfl_down(a2, off); a3 += __shfl_down(a3, off);
    }
    if (lane == 0) ((float4*)q_agg)[n] = make_float4(a0, a1, a2, a3);
}

// ---------------------------------------------------------------------------
// K7 v6: fused softmax + weighted aggregation -> out fp32
//   Pass A v2: split reduction (butterfly-max, 4 exps total, butterfly-sum);
//   softmax is shift-invariant so any uniform M works -> exact same result,
//   44 fewer transcendentals per node than the online-merge butterfly.
//   e_h reused for pass B's alpha (no per-edge recompute).
//   Pass B v2: QUAD-edge broadcast - each 16-lane quarter owns one edge,
//   dwordx4 (16B, 8 bf16 dims) per lane: shfl/edge and VMEM-instr/edge
//   halve vs dual-edge. Cross-quarter reduce via shfl_down(32,16).
// ---------------------------------------------------------------------------
__global__ __launch_bounds__(256) void attn_kernel(
    const int* __restrict__ cursor, const int* __restrict__ csr_col,
    const int* __restrict__ ovf_cnt, const u32* __restrict__ ovf,
    const float* __restrict__ k_act, const float* __restrict__ q_agg,
    const u16* __restrict__ h_projb, float* __restrict__ out)
{
    const int wave = threadIdx.x >> 6, lane = threadIdx.x & 63;
    const int n = blockIdx.x * 4 + wave;
    if (n >= N_NODES) return;
    const int deg = cursor[n];
    const int prim = min(deg, CAP);
    const float4 k4 = ((const float4*)k_act)[n];

    // ---- pass A: scores (slot = lane), split max/sum reduction ----
    int cA = 0;
    float sA0 = -1e30f, sA1 = -1e30f, sA2 = -1e30f, sA3 = -1e30f;
    if (lane < prim) {
        cA = csr_col[n * CAP + lane];
        const float4 q = ((const float4*)q_agg)[cA];
        sA0 = k4.x * q.x; sA1 = k4.y * q.y;
        sA2 = k4.z * q.z; sA3 = k4.w * q.w;
    }
    float m0 = sA0, m1 = sA1, m2 = sA2, m3 = sA3;
    const int ovf_n = (deg > CAP) ? *ovf_cnt : 0;
    // rare-path: fold overflow-edge scores into the max
    for (int i = lane; i < ovf_n; i += 64) {
        const u32 pk = ovf[i];
        if ((int)(pk >> 16) != n) continue;
        const float4 q = ((const float4*)q_agg)[pk & 0xffffu];
        m0 = fmaxf(m0, k4.x * q.x); m1 = fmaxf(m1, k4.y * q.y);
        m2 = fmaxf(m2, k4.z * q.z); m3 = fmaxf(m3, k4.w * q.w);
    }
    #pragma unroll
    for (int off = 32; off > 0; off >>= 1) {
        m0 = fmaxf(m0, __shfl_xor(m0, off));
        m1 = fmaxf(m1, __shfl_xor(m1, off));
        m2 = fmaxf(m2, __shfl_xor(m2, off));
        m3 = fmaxf(m3, __shfl_xor(m3, off));
    }
    // e for this lane's primary slot (0 for invalid lanes: exp(-1e30-m)=0;
    // deg==0 gives exp(0)=1 but pass B is skipped then)
    const float e0 = __expf(sA0 - m0), e1 = __expf(sA1 - m1);
    const float e2 = __expf(sA2 - m2), e3 = __expf(sA3 - m3);
    float u0 = e0, u1 = e1, u2 = e2, u3 = e3;
    // rare-path: overflow-edge exp contributions to the denominator
    for (int i = lane; i < ovf_n; i += 64) {
        const u32 pk = ovf[i];
        if ((int)(pk >> 16) != n) continue;
        const float4 q = ((const float4*)q_agg)[pk & 0xffffu];
        u0 += __expf(k4.x * q.x - m0); u1 += __expf(k4.y * q.y - m1);
        u2 += __expf(k4.z * q.z - m2); u3 += __expf(k4.w * q.w - m3);
    }
    #pragma unroll
    for (int off = 32; off > 0; off >>= 1) {
        u0 += __shfl_xor(u0, off); u1 += __shfl_xor(u1, off);
        u2 += __shfl_xor(u2, off); u3 += __shfl_xor(u3, off);
    }
    const float r0 = 0.25f / (u0 + 1e-8f), r1 = 0.25f / (u1 + 1e-8f);
    const float r2 = 0.25f / (u2 + 1e-8f), r3 = 0.25f / (u3 + 1e-8f);
    const float a_s = e0 * r0 + e1 * r1 + e2 * r2 + e3 * r3;  // lane's alpha

    // ---- pass B: quad-edge broadcast accumulate ----
    const int sub4 = lane & 15;          // dim group: dims 8*sub4 .. 8*sub4+7
    const int eh4  = lane >> 4;          // which edge of the quad (0..3)
    float acc[8] = {0.f, 0.f, 0.f, 0.f, 0.f, 0.f, 0.f, 0.f};
    const uint4* hp4 = (const uint4*)h_projb;   // row stride = 16 uint4 (256 B)

    #pragma unroll 4
    for (int j = 0; j < prim; j += 4) {
        // quarter eh4 takes edge j+eh4; slots >= prim have a_s == 0
        const int   c = __shfl(cA,  j + eh4);
        const float a = __shfl(a_s, j + eh4);
        const uint4 w = hp4[(size_t)c * 16 + sub4];
        acc[0] = fmaf(a, bflo(w.x), acc[0]);
        acc[1] = fmaf(a, bfhi(w.x), acc[1]);
        acc[2] = fmaf(a, bflo(w.y), acc[2]);
        acc[3] = fmaf(a, bfhi(w.y), acc[3]);
        acc[4] = fmaf(a, bflo(w.z), acc[4]);
        acc[5] = fmaf(a, bfhi(w.z), acc[5]);
        acc[6] = fmaf(a, bflo(w.w), acc[6]);
        acc[7] = fmaf(a, bfhi(w.w), acc[7]);
    }
    // rare-path overflow edges (deg > CAP): exact recompute + same broadcast
    for (int base = 0; base < ovf_n; base += 64) {
        const int i = base + lane;
        int   c_s = 0;
        float a_v = 0.f;
        if (i < ovf_n) {
            const u32 pk = ovf[i];
            if ((int)(pk >> 16) == n) {
                c_s = (int)(pk & 0xffffu);
                const float4 q = ((const float4*)q_agg)[c_s];
                a_v = __expf(k4.x * q.x - m0) * r0 + __expf(k4.y * q.y - m1) * r1
                    + __expf(k4.z * q.z - m2) * r2 + __expf(k4.w * q.w - m3) * r3;
            }
        }
        const int cnt = min(64, ovf_n - base);
        for (int j = 0; j < cnt; j += 4) {
            const int   jj = j + eh4;
            const int   c = __shfl(c_s, jj);      // lanes past cnt hold a_v=0
            const float a = __shfl(a_v, jj);
            const uint4 w = hp4[(size_t)c * 16 + sub4];
            acc[0] = fmaf(a, bflo(w.x), acc[0]);
            acc[1] = fmaf(a, bfhi(w.x), acc[1]);
            acc[2] = fmaf(a, bflo(w.y), acc[2]);
            acc[3] = fmaf(a, bfhi(w.y), acc[3]);
            acc[4] = fmaf(a, bflo(w.z), acc[4]);
            acc[5] = fmaf(a, bfhi(w.z), acc[5]);
            acc[6] = fmaf(a, bflo(w.w), acc[6]);
            acc[7] = fmaf(a, bfhi(w.w), acc[7]);
        }
    }
    // combine the four quarters, then 16-lane 2x float4 store
    #pragma unroll
    for (int d = 0; d < 8; ++d) {
        acc[d] += __shfl_down(acc[d], 32);
        acc[d] += __shfl_down(acc[d], 16);
    }
    if (eh4 == 0) {
        ((float4*)out)[(size_t)n * 32 + sub4 * 2] =
            make_float4(leaky(acc[0]), leaky(acc[1]), leaky(acc[2]), leaky(acc[3]));
        ((float4*)out)[(size_t)n * 32 + sub4 * 2 + 1] =
            make_float4(leaky(acc[4]), leaky(acc[5]), leaky(acc[6]), leaky(acc[7]));
    }
}

// ---------------------------------------------------------------------------
extern "C" void kernel_launch(void* const* d_in, const int* in_sizes, int n_in,
                              void* d_out, int out_size, void* d_ws, size_t ws_size,
                              hipStream_t stream)
{
    const void* x  = d_in[0];
    const void* ei = d_in[1];
    const void* Wq = d_in[2];
    const void* Wk = d_in[3];
    const void* Wl = d_in[4];
    const void* bl = d_in[5];
    float* out = (float*)d_out;   // reference output dtype = float32

    char* ws = (char*)d_ws;
    size_t off = 0;
    auto alloc = [&](size_t bytes) -> size_t {
        off = (off + 255) & ~(size_t)255;
        size_t o = off; off += bytes; return o;
    };
    const size_t o_flag  = alloc(256);
    const size_t o_wf    = alloc((size_t)W_TOTAL * sizeof(float));
    const size_t o_hq    = alloc((size_t)N_NODES * NHEADS * sizeof(float));
    const size_t o_kact  = alloc((size_t)N_NODES * NHEADS * sizeof(float));
    const size_t o_qagg  = alloc((size_t)N_NODES * NHEADS * sizeof(float));
    const size_t o_hproj = alloc((size_t)N_NODES * DIM * sizeof(u16));
    const size_t o_cur   = alloc((size_t)N_NODES * sizeof(int));   // zeroed
    const size_t o_ovfc  = alloc(256);                             // zeroed
    const size_t o_csr   = alloc((size_t)N_NODES * CAP * sizeof(int)); // 12.8 MB
    const size_t o_ovf   = alloc((size_t)N_EDGES * sizeof(u32));       // 6.4 MB
    (void)ws_size;   // ~35 MB total, ws_size proven >= 45.9 MB in r7

    int*   flags   = (int*)(ws + o_flag);
    float* wf      = (float*)(ws + o_wf);
    float* h_q     = (float*)(ws + o_hq);
    float* k_act   = (float*)(ws + o_kact);
    float* q_agg   = (float*)(ws + o_qagg);
    u16*   h_projb = (u16*)(ws + o_hproj);
    int*   cursor  = (int*)(ws + o_cur);
    int*   ovf_cnt = (int*)(ws + o_ovfc);
    int*   csr_col = (int*)(ws + o_csr);
    u32*   ovf     = (u32*)(ws + o_ovf);

    // zero cursor + overflow counter in one memset (contiguous regions)
    hipMemsetAsync(ws + o_cur, 0, (o_ovfc - o_cur) + 256, stream);

    detect_all_kernel<<<1, 64, 0, stream>>>(
        (const u32*)x, (const u32*)Wq, (const u32*)Wk, (const u32*)Wl,
        (const u32*)bl, (const u32*)ei, flags);
    canon_w_kernel<<<(W_TOTAL + 255) / 256, 256, 0, stream>>>(Wq, Wk, Wl, bl, flags, wf);
    // MFMA GEMM: h_proj + h_q + k_act in one kernel (64 rows/block)
    proj_kernel<<<(N_NODES + 63) / 64, 256, 0, stream>>>(
        x, flags, wf, h_projb, h_q, k_act);
    // 1024 edge-chunks x 8 slices
    csr_kernel<<<1024 * NSLICE, 256, 0, stream>>>(ei, flags, cursor, csr_col,
                                                  ovf_cnt, ovf);
    qagg_kernel<<<N_NODES / 4, 256, 0, stream>>>(cursor, csr_col, ovf_cnt, ovf,
                                                 h_q, q_agg);
    attn_kernel<<<N_NODES / 4, 256, 0, stream>>>(cursor, csr_col, ovf_cnt, ovf,
                                                 k_act, q_agg, h_projb, out);
}